// Round 2
// baseline (2306.893 us; speedup 1.0000x reference)
//
#include <hip/hip_runtime.h>
#include <hip/hip_bf16.h>

constexpr int N    = 50000;
constexpr int E    = 800000;
constexpr int FIN  = 64;
constexpr int FMID = 128;
constexpr int FOUT = 64;
constexpr int G    = 512;

__global__ void k_init_deg(float* __restrict__ deg) {
    int i = blockIdx.x * blockDim.x + threadIdx.x;
    if (i < N) deg[i] = 1.0f;   // self-loop
}

__global__ void k_deg_accum(const int* __restrict__ dst, float* __restrict__ deg) {
    int e = blockIdx.x * blockDim.x + threadIdx.x;
    if (e < E) atomicAdd(&deg[dst[e]], 1.0f);
}

__global__ void k_dinv(float* __restrict__ deg) {
    int i = blockIdx.x * blockDim.x + threadIdx.x;
    if (i < N) deg[i] = rsqrtf(deg[i]);   // deg >= 1 always
}

__global__ void k_norm(const int* __restrict__ src, const int* __restrict__ dst,
                       const float* __restrict__ dinv, float* __restrict__ norm) {
    int e = blockIdx.x * blockDim.x + threadIdx.x;
    if (e < E) norm[e] = dinv[src[e]] * dinv[dst[e]];
}

// h1[i][f] = sum_k x[i][k] * W1[k][f];  one node per 128-thread block
__global__ void k_gemm1(const float* __restrict__ x, const float* __restrict__ W1,
                        float* __restrict__ h1) {
    __shared__ float xs[FIN];
    int i = blockIdx.x;
    int t = threadIdx.x;               // 0..127 -> output feature
    if (t < FIN) xs[t] = x[i * FIN + t];
    __syncthreads();
    float acc = 0.f;
#pragma unroll
    for (int k = 0; k < FIN; ++k)
        acc += xs[k] * W1[k * FMID + t];
    h1[i * FMID + t] = acc;
}

// o1[i][f] = b1[f] + dinv[i]^2 * h1[i][f]   (self-loop term folded in)
__global__ void k_init_o1(const float* __restrict__ h1, const float* __restrict__ dinv,
                          const float* __restrict__ b1, float* __restrict__ o1) {
    int idx = blockIdx.x * blockDim.x + threadIdx.x;   // over N*FMID/4
    if (idx >= N * (FMID / 4)) return;
    int i = idx / (FMID / 4);
    int c = idx % (FMID / 4);
    float d2 = dinv[i] * dinv[i];
    float4 h = reinterpret_cast<const float4*>(h1)[idx];
    float4 b = reinterpret_cast<const float4*>(b1)[c];
    float4 o;
    o.x = b.x + d2 * h.x;
    o.y = b.y + d2 * h.y;
    o.z = b.z + d2 * h.z;
    o.w = b.w + d2 * h.w;
    reinterpret_cast<float4*>(o1)[idx] = o;
}

// edge-parallel scatter: 32 lanes per edge, float4 each
__global__ void k_agg1(const int* __restrict__ src, const int* __restrict__ dst,
                       const float* __restrict__ norm, const float* __restrict__ h1,
                       float* __restrict__ o1) {
    int tid = blockIdx.x * blockDim.x + threadIdx.x;   // E*32 = 25.6M
    if (tid >= E * 32) return;
    int e = tid >> 5, c = tid & 31;
    int s = src[e], d = dst[e];
    float w = norm[e];
    float4 h = reinterpret_cast<const float4*>(h1 + (size_t)s * FMID)[c];
    float* o = o1 + (size_t)d * FMID + c * 4;
    atomicAdd(o + 0, w * h.x);
    atomicAdd(o + 1, w * h.y);
    atomicAdd(o + 2, w * h.z);
    atomicAdd(o + 3, w * h.w);
}

// h2[i][f] = sum_k relu(o1[i][k]) * W2[k][f];  4 nodes per 256-thread block
__global__ void k_gemm2(const float* __restrict__ o1, const float* __restrict__ W2,
                        float* __restrict__ h2) {
    __shared__ float xs[4][FMID];
    int ln = threadIdx.x >> 6;         // local node 0..3
    int lt = threadIdx.x & 63;         // output feature 0..63
    int i = blockIdx.x * 4 + ln;
    xs[ln][lt]      = fmaxf(o1[(size_t)i * FMID + lt], 0.f);
    xs[ln][lt + 64] = fmaxf(o1[(size_t)i * FMID + lt + 64], 0.f);
    __syncthreads();
    float acc = 0.f;
#pragma unroll
    for (int k = 0; k < FMID; ++k)
        acc += xs[ln][k] * W2[k * FOUT + lt];
    h2[(size_t)i * FOUT + lt] = acc;
}

__global__ void k_init_o2(const float* __restrict__ h2, const float* __restrict__ dinv,
                          const float* __restrict__ b2, float* __restrict__ o2) {
    int idx = blockIdx.x * blockDim.x + threadIdx.x;   // over N*FOUT/4
    if (idx >= N * (FOUT / 4)) return;
    int i = idx / (FOUT / 4);
    int c = idx % (FOUT / 4);
    float d2 = dinv[i] * dinv[i];
    float4 h = reinterpret_cast<const float4*>(h2)[idx];
    float4 b = reinterpret_cast<const float4*>(b2)[c];
    float4 o;
    o.x = b.x + d2 * h.x;
    o.y = b.y + d2 * h.y;
    o.z = b.z + d2 * h.z;
    o.w = b.w + d2 * h.w;
    reinterpret_cast<float4*>(o2)[idx] = o;
}

__global__ void k_agg2(const int* __restrict__ src, const int* __restrict__ dst,
                       const float* __restrict__ norm, const float* __restrict__ h2,
                       float* __restrict__ o2) {
    int tid = blockIdx.x * blockDim.x + threadIdx.x;   // E*16 = 12.8M
    if (tid >= E * 16) return;
    int e = tid >> 4, c = tid & 15;
    int s = src[e], d = dst[e];
    float w = norm[e];
    float4 h = reinterpret_cast<const float4*>(h2 + (size_t)s * FOUT)[c];
    float* o = o2 + (size_t)d * FOUT + c * 4;
    atomicAdd(o + 0, w * h.x);
    atomicAdd(o + 1, w * h.y);
    atomicAdd(o + 2, w * h.z);
    atomicAdd(o + 3, w * h.w);
}

__global__ void k_pool_zero(float* __restrict__ sums, float* __restrict__ counts) {
    int i = blockIdx.x * blockDim.x + threadIdx.x;
    if (i < G * FOUT) sums[i] = 0.f;
    if (i < G) counts[i] = 0.f;
}

__global__ void k_pool(const float* __restrict__ o2, const int* __restrict__ batch,
                       float* __restrict__ sums, float* __restrict__ counts) {
    int tid = blockIdx.x * blockDim.x + threadIdx.x;   // N*16
    if (tid >= N * 16) return;
    int i = tid >> 4, c = tid & 15;
    int g = batch[i];
    float4 v = reinterpret_cast<const float4*>(o2 + (size_t)i * FOUT)[c];
    float* s = sums + (size_t)g * FOUT + c * 4;
    atomicAdd(s + 0, v.x);
    atomicAdd(s + 1, v.y);
    atomicAdd(s + 2, v.z);
    atomicAdd(s + 3, v.w);
    if (c == 0) atomicAdd(&counts[g], 1.0f);
}

__global__ void k_final(const float* __restrict__ sums, const float* __restrict__ counts,
                        float* __restrict__ out) {
    int idx = blockIdx.x * blockDim.x + threadIdx.x;
    if (idx >= G * FOUT) return;
    int g = idx / FOUT;
    out[idx] = sums[idx] / fmaxf(counts[g], 1.0f);
}

extern "C" void kernel_launch(void* const* d_in, const int* in_sizes, int n_in,
                              void* d_out, int out_size, void* d_ws, size_t ws_size,
                              hipStream_t stream) {
    const float* x     = (const float*)d_in[0];
    const int*   ei    = (const int*)d_in[1];
    const int*   batch = (const int*)d_in[2];
    const float* W1    = (const float*)d_in[3];
    const float* b1    = (const float*)d_in[4];
    const float* W2    = (const float*)d_in[5];
    const float* b2    = (const float*)d_in[6];
    float* out = (float*)d_out;

    const int* srcp = ei;        // edge_index[0]
    const int* dstp = ei + E;    // edge_index[1]

    char* ws = (char*)d_ws;
    // layout (bytes), 512-aligned offsets
    float* dinv = (float*)(ws + 0);                    //   200,000 -> pad to 200,704
    float* norm = (float*)(ws + 200704);               // 3,200,000
    float* h1   = (float*)(ws + 3400704);              // 25,600,000  [3400704, 29000704)
    float* o1   = (float*)(ws + 29000704);             // 25,600,000  [29000704, 54600704)
    // h1 dead after agg1: alias h2/o2 onto its region
    float* h2   = h1;                                  // 12,800,000  [3400704, 16200704)
    float* o2   = (float*)(ws + 3400704 + 12800000);   // 12,800,000  [16200704, 29000704)
    // norm dead after agg2: alias pool buffers onto it
    float* sums   = norm;                              // 131,072
    float* counts = (float*)(ws + 200704 + 131072);    // 2,048

    dim3 B(256);

    k_init_deg<<<dim3((N + 255) / 256), B, 0, stream>>>(dinv);
    k_deg_accum<<<dim3((E + 255) / 256), B, 0, stream>>>(dstp, dinv);
    k_dinv<<<dim3((N + 255) / 256), B, 0, stream>>>(dinv);
    k_norm<<<dim3((E + 255) / 256), B, 0, stream>>>(srcp, dstp, dinv, norm);

    k_gemm1<<<dim3(N), dim3(128), 0, stream>>>(x, W1, h1);
    k_init_o1<<<dim3((N * (FMID / 4) + 255) / 256), B, 0, stream>>>(h1, dinv, b1, o1);
    k_agg1<<<dim3(((size_t)E * 32 + 255) / 256), B, 0, stream>>>(srcp, dstp, norm, h1, o1);

    k_gemm2<<<dim3(N / 4), B, 0, stream>>>(o1, W2, h2);
    k_init_o2<<<dim3((N * (FOUT / 4) + 255) / 256), B, 0, stream>>>(h2, dinv, b2, o2);
    k_agg2<<<dim3(((size_t)E * 16 + 255) / 256), B, 0, stream>>>(srcp, dstp, norm, h2, o2);

    k_pool_zero<<<dim3((G * FOUT + 255) / 256), B, 0, stream>>>(sums, counts);
    k_pool<<<dim3((N * 16 + 255) / 256), B, 0, stream>>>(o2, batch, sums, counts);
    k_final<<<dim3((G * FOUT + 255) / 256), B, 0, stream>>>(sums, counts, out);
}

// Round 3
// 334.812 us; speedup vs baseline: 6.8901x; 6.8901x over previous
//
#include <hip/hip_runtime.h>

constexpr int N    = 50000;
constexpr int E    = 800000;
constexpr int FIN  = 64;
constexpr int FMID = 128;
constexpr int FOUT = 64;
constexpr int G    = 512;
constexpr int SCAN_ITEMS = 1024;
constexpr int NB_SCAN = (N + SCAN_ITEMS - 1) / SCAN_ITEMS;   // 49

__global__ void k_zero_edeg(int* __restrict__ edeg) {
    int i = blockIdx.x * blockDim.x + threadIdx.x;
    if (i < N) edeg[i] = 0;
}

__global__ void k_deg(const int* __restrict__ dst, int* __restrict__ edeg) {
    int e = blockIdx.x * blockDim.x + threadIdx.x;
    if (e < E) atomicAdd(&edeg[dst[e]], 1);
}

// block-level exclusive scan of edeg (1024 items / block)
__global__ __launch_bounds__(256) void k_scan1(const int* __restrict__ edeg,
                                               int* __restrict__ row_ptr,
                                               int* __restrict__ bsum) {
    __shared__ int s[256];
    int t = threadIdx.x;
    int base = blockIdx.x * SCAN_ITEMS + t * 4;
    int v0 = (base + 0 < N) ? edeg[base + 0] : 0;
    int v1 = (base + 1 < N) ? edeg[base + 1] : 0;
    int v2 = (base + 2 < N) ? edeg[base + 2] : 0;
    int v3 = (base + 3 < N) ? edeg[base + 3] : 0;
    int tsum = v0 + v1 + v2 + v3;
    s[t] = tsum;
    __syncthreads();
    for (int off = 1; off < 256; off <<= 1) {
        int add = (t >= off) ? s[t - off] : 0;
        __syncthreads();
        s[t] += add;
        __syncthreads();
    }
    int texcl = s[t] - tsum;
    if (t == 255) bsum[blockIdx.x] = s[255];
    if (base + 0 < N) row_ptr[base + 0] = texcl;
    if (base + 1 < N) row_ptr[base + 1] = texcl + v0;
    if (base + 2 < N) row_ptr[base + 2] = texcl + v0 + v1;
    if (base + 3 < N) row_ptr[base + 3] = texcl + v0 + v1 + v2;
}

__global__ void k_scan2(int* __restrict__ bsum) {
    if (threadIdx.x == 0 && blockIdx.x == 0) {
        int run = 0;
        for (int b = 0; b < NB_SCAN; ++b) { int v = bsum[b]; bsum[b] = run; run += v; }
    }
}

__global__ void k_scan3(const int* __restrict__ edeg, int* __restrict__ row_ptr,
                        const int* __restrict__ bsum, int* __restrict__ cursor,
                        float* __restrict__ dinv) {
    int i = blockIdx.x * blockDim.x + threadIdx.x;
    if (i >= N) return;
    int rp = row_ptr[i] + bsum[i / SCAN_ITEMS];
    row_ptr[i] = rp;
    cursor[i] = rp;
    dinv[i] = rsqrtf(1.0f + (float)edeg[i]);
    if (i == 0) row_ptr[N] = E;
}

__global__ void k_scatter(const int* __restrict__ src, const int* __restrict__ dst,
                          const float* __restrict__ dinv, int* __restrict__ cursor,
                          int* __restrict__ csr_src, float* __restrict__ csr_w) {
    int e = blockIdx.x * blockDim.x + threadIdx.x;
    if (e >= E) return;
    int s = src[e], d = dst[e];
    int slot = atomicAdd(&cursor[d], 1);
    csr_src[slot] = s;
    csr_w[slot] = dinv[s] * dinv[d];
}

// xa[i] = dinv[i]^2 * x[i] + sum_{e in CSR[i]} w_e * x[src_e]   (64 feats, lane=feat)
__global__ void k_agg_x(const float* __restrict__ x, const int* __restrict__ rp,
                        const int* __restrict__ cs, const float* __restrict__ cw,
                        const float* __restrict__ dinv, float* __restrict__ xa) {
    int wv = threadIdx.x >> 6, lane = threadIdx.x & 63;
    int node = blockIdx.x * 4 + wv;
    if (node >= N) return;
    int beg = rp[node], end = rp[node + 1];
    float di = dinv[node];
    float acc = di * di * x[(size_t)node * FIN + lane];
    for (int e = beg; e < end; ++e) {
        int s = cs[e];
        float w = cw[e];
        acc += w * x[(size_t)s * FIN + lane];
    }
    xa[(size_t)node * FIN + lane] = acc;
}

// h1r = relu(xa @ W1 + b1); 64 nodes/block, 256 threads, reg-blocked 8x4
__global__ __launch_bounds__(256) void k_gemm1(const float* __restrict__ xa,
                                               const float* __restrict__ W1,
                                               const float* __restrict__ b1,
                                               float* __restrict__ h1r) {
    __shared__ float Ws[FIN * FMID];   // [k][c] 32KB
    __shared__ float Xs[64 * FIN];     // [r][k] 16KB
    int t = threadIdx.x;
    int n0 = blockIdx.x * 64;
    float4* Ws4 = (float4*)Ws;
    const float4* W14 = (const float4*)W1;
#pragma unroll
    for (int i = 0; i < 8; ++i) Ws4[t + i * 256] = W14[t + i * 256];
    float4* Xs4 = (float4*)Xs;
    const float4* xa4 = (const float4*)xa;
#pragma unroll
    for (int i = 0; i < 4; ++i) {
        int j = t + i * 256;
        int r = j >> 4, c4 = j & 15;
        int n = n0 + r;
        Xs4[j] = (n < N) ? xa4[(size_t)n * 16 + c4] : float4{0.f, 0.f, 0.f, 0.f};
    }
    __syncthreads();
    int colg = t & 31, rowi = t >> 5;     // cols 4*colg (128), rows rowi + 8*rr (64)
    float acc[8][4];
#pragma unroll
    for (int a = 0; a < 8; ++a)
#pragma unroll
        for (int b = 0; b < 4; ++b) acc[a][b] = 0.f;
#pragma unroll 4
    for (int k = 0; k < FIN; ++k) {
        float4 w = ((float4*)(Ws + k * FMID))[colg];
#pragma unroll
        for (int rr = 0; rr < 8; ++rr) {
            float xv = Xs[(rowi + rr * 8) * FIN + k];
            acc[rr][0] += xv * w.x;
            acc[rr][1] += xv * w.y;
            acc[rr][2] += xv * w.z;
            acc[rr][3] += xv * w.w;
        }
    }
    float4 bb = ((const float4*)b1)[colg];
#pragma unroll
    for (int rr = 0; rr < 8; ++rr) {
        int n = n0 + rowi + rr * 8;
        if (n < N) {
            float4 o;
            o.x = fmaxf(acc[rr][0] + bb.x, 0.f);
            o.y = fmaxf(acc[rr][1] + bb.y, 0.f);
            o.z = fmaxf(acc[rr][2] + bb.z, 0.f);
            o.w = fmaxf(acc[rr][3] + bb.w, 0.f);
            ((float4*)(h1r + (size_t)n * FMID))[colg] = o;
        }
    }
}

// h2 = h1r @ W2; 32 nodes/block, 256 threads, reg-blocked 2x4
__global__ __launch_bounds__(256) void k_gemm2(const float* __restrict__ h1r,
                                               const float* __restrict__ W2,
                                               float* __restrict__ h2) {
    __shared__ float Ws[FMID * FOUT];  // [k][c] 32KB
    __shared__ float Xs[32 * FMID];    // [r][k] 16KB
    int t = threadIdx.x;
    int n0 = blockIdx.x * 32;
    float4* Ws4 = (float4*)Ws;
    const float4* W24 = (const float4*)W2;
#pragma unroll
    for (int i = 0; i < 8; ++i) Ws4[t + i * 256] = W24[t + i * 256];
    float4* Xs4 = (float4*)Xs;
    const float4* h4 = (const float4*)h1r;
#pragma unroll
    for (int i = 0; i < 4; ++i) {
        int j = t + i * 256;
        int r = j >> 5, c4 = j & 31;
        int n = n0 + r;
        Xs4[j] = (n < N) ? h4[(size_t)n * 32 + c4] : float4{0.f, 0.f, 0.f, 0.f};
    }
    __syncthreads();
    int colg = t & 15, rowi = t >> 4;     // cols 4*colg (64), rows rowi + 16*rr (32)
    float acc[2][4];
#pragma unroll
    for (int a = 0; a < 2; ++a)
#pragma unroll
        for (int b = 0; b < 4; ++b) acc[a][b] = 0.f;
#pragma unroll 4
    for (int k = 0; k < FMID; ++k) {
        float4 w = ((float4*)(Ws + k * FOUT))[colg];
#pragma unroll
        for (int rr = 0; rr < 2; ++rr) {
            float xv = Xs[(rowi + rr * 16) * FMID + k];
            acc[rr][0] += xv * w.x;
            acc[rr][1] += xv * w.y;
            acc[rr][2] += xv * w.z;
            acc[rr][3] += xv * w.w;
        }
    }
#pragma unroll
    for (int rr = 0; rr < 2; ++rr) {
        int n = n0 + rowi + rr * 16;
        if (n < N) {
            float4 o = {acc[rr][0], acc[rr][1], acc[rr][2], acc[rr][3]};
            ((float4*)(h2 + (size_t)n * FOUT))[colg] = o;
        }
    }
}

// o2[i] = b2 + dinv^2*h2[i] + sum w*h2[src]
__global__ void k_agg2(const float* __restrict__ h2, const int* __restrict__ rp,
                       const int* __restrict__ cs, const float* __restrict__ cw,
                       const float* __restrict__ dinv, const float* __restrict__ b2,
                       float* __restrict__ o2) {
    int wv = threadIdx.x >> 6, lane = threadIdx.x & 63;
    int node = blockIdx.x * 4 + wv;
    if (node >= N) return;
    int beg = rp[node], end = rp[node + 1];
    float di = dinv[node];
    float acc = b2[lane] + di * di * h2[(size_t)node * FOUT + lane];
    for (int e = beg; e < end; ++e) {
        int s = cs[e];
        float w = cw[e];
        acc += w * h2[(size_t)s * FOUT + lane];
    }
    o2[(size_t)node * FOUT + lane] = acc;
}

// one block per graph; batch is sorted -> binary search the node range
__global__ void k_pool(const float* __restrict__ o2, const int* __restrict__ batch,
                       float* __restrict__ out) {
    int g = blockIdx.x, lane = threadIdx.x;
    int lo = 0, hi = N;
    while (lo < hi) { int m = (lo + hi) >> 1; if (batch[m] < g) lo = m + 1; else hi = m; }
    int start = lo;
    hi = N;
    while (lo < hi) { int m = (lo + hi) >> 1; if (batch[m] < g + 1) lo = m + 1; else hi = m; }
    int end = lo;
    float acc = 0.f;
    for (int n = start; n < end; ++n) acc += o2[(size_t)n * FOUT + lane];
    out[g * FOUT + lane] = acc / fmaxf((float)(end - start), 1.f);
}

extern "C" void kernel_launch(void* const* d_in, const int* in_sizes, int n_in,
                              void* d_out, int out_size, void* d_ws, size_t ws_size,
                              hipStream_t stream) {
    const float* x     = (const float*)d_in[0];
    const int*   ei    = (const int*)d_in[1];
    const int*   batch = (const int*)d_in[2];
    const float* W1    = (const float*)d_in[3];
    const float* b1    = (const float*)d_in[4];
    const float* W2    = (const float*)d_in[5];
    const float* b2    = (const float*)d_in[6];
    float* out = (float*)d_out;

    const int* srcp = ei;        // edge_index[0]
    const int* dstp = ei + E;    // edge_index[1]

    char* ws = (char*)d_ws;
    // layout (bytes, 512-aligned)
    int*   edeg    = (int*)  (ws + 0);          //   200,000 -> 200,704
    int*   cursor  = (int*)  (ws + 200704);     //   200,000 -> 401,408
    float* dinv    = (float*)(ws + 401408);     //   200,000 -> 602,112
    int*   row_ptr = (int*)  (ws + 602112);     //   200,004 -> 802,816
    int*   bsum    = (int*)  (ws + 802816);     //       256 -> 803,328
    int*   csr_src = (int*)  (ws + 803328);     // 3,200,000 -> 4,003,328
    float* csr_w   = (float*)(ws + 4003328);    // 3,200,000 -> 7,203,328
    float* xa      = (float*)(ws + 7203328);    // 12,800,000 -> 20,003,328
    float* h1r     = (float*)(ws + 20003328);   // 25,600,000 -> 45,603,328
    // lifetimes: xa dead after gemm1 -> h2 aliases xa; h1r dead after gemm2 -> o2 aliases h1r
    float* h2 = xa;
    float* o2 = h1r;

    dim3 B(256);

    k_zero_edeg<<<dim3((N + 255) / 256), B, 0, stream>>>(edeg);
    k_deg<<<dim3((E + 255) / 256), B, 0, stream>>>(dstp, edeg);
    k_scan1<<<dim3(NB_SCAN), B, 0, stream>>>(edeg, row_ptr, bsum);
    k_scan2<<<dim3(1), dim3(64), 0, stream>>>(bsum);
    k_scan3<<<dim3((N + 255) / 256), B, 0, stream>>>(edeg, row_ptr, bsum, cursor, dinv);
    k_scatter<<<dim3((E + 255) / 256), B, 0, stream>>>(srcp, dstp, dinv, cursor, csr_src, csr_w);

    k_agg_x<<<dim3((N + 3) / 4), B, 0, stream>>>(x, row_ptr, csr_src, csr_w, dinv, xa);
    k_gemm1<<<dim3((N + 63) / 64), B, 0, stream>>>(xa, W1, b1, h1r);
    k_gemm2<<<dim3((N + 31) / 32), B, 0, stream>>>(h1r, W2, h2);
    k_agg2<<<dim3((N + 3) / 4), B, 0, stream>>>(h2, row_ptr, csr_src, csr_w, dinv, b2, o2);
    k_pool<<<dim3(G), dim3(FOUT), 0, stream>>>(o2, batch, out);
}

// Round 4
// 213.837 us; speedup vs baseline: 10.7881x; 1.5657x over previous
//
#include <hip/hip_runtime.h>

constexpr int N    = 50000;
constexpr int E    = 800000;
constexpr int FIN  = 64;
constexpr int FMID = 128;
constexpr int FOUT = 64;
constexpr int G    = 512;
constexpr int SCAN_ITEMS = 1024;
constexpr int NB_SCAN = (N + SCAN_ITEMS - 1) / SCAN_ITEMS;   // 49

__global__ void k_zero_edeg(int* __restrict__ edeg) {
    int i = blockIdx.x * blockDim.x + threadIdx.x;
    if (i < N) edeg[i] = 0;
}

__global__ void k_deg(const int* __restrict__ dst, int* __restrict__ edeg) {
    int e = blockIdx.x * blockDim.x + threadIdx.x;
    if (e < E) atomicAdd(&edeg[dst[e]], 1);
}

// block-level exclusive scan of edeg (1024 items / block)
__global__ __launch_bounds__(256) void k_scan1(const int* __restrict__ edeg,
                                               int* __restrict__ row_ptr,
                                               int* __restrict__ bsum) {
    __shared__ int s[256];
    int t = threadIdx.x;
    int base = blockIdx.x * SCAN_ITEMS + t * 4;
    int v0 = (base + 0 < N) ? edeg[base + 0] : 0;
    int v1 = (base + 1 < N) ? edeg[base + 1] : 0;
    int v2 = (base + 2 < N) ? edeg[base + 2] : 0;
    int v3 = (base + 3 < N) ? edeg[base + 3] : 0;
    int tsum = v0 + v1 + v2 + v3;
    s[t] = tsum;
    __syncthreads();
    for (int off = 1; off < 256; off <<= 1) {
        int add = (t >= off) ? s[t - off] : 0;
        __syncthreads();
        s[t] += add;
        __syncthreads();
    }
    int texcl = s[t] - tsum;
    if (t == 255) bsum[blockIdx.x] = s[255];
    if (base + 0 < N) row_ptr[base + 0] = texcl;
    if (base + 1 < N) row_ptr[base + 1] = texcl + v0;
    if (base + 2 < N) row_ptr[base + 2] = texcl + v0 + v1;
    if (base + 3 < N) row_ptr[base + 3] = texcl + v0 + v1 + v2;
}

__global__ void k_scan2(int* __restrict__ bsum) {
    if (threadIdx.x == 0 && blockIdx.x == 0) {
        int run = 0;
        for (int b = 0; b < NB_SCAN; ++b) { int v = bsum[b]; bsum[b] = run; run += v; }
    }
}

__global__ void k_scan3(const int* __restrict__ edeg, int* __restrict__ row_ptr,
                        const int* __restrict__ bsum, int* __restrict__ cursor,
                        float* __restrict__ dinv) {
    int i = blockIdx.x * blockDim.x + threadIdx.x;
    if (i >= N) return;
    int rp = row_ptr[i] + bsum[i / SCAN_ITEMS];
    row_ptr[i] = rp;
    cursor[i] = rp;
    dinv[i] = rsqrtf(1.0f + (float)edeg[i]);
    if (i == 0) row_ptr[N] = E;
}

__global__ void k_scatter(const int* __restrict__ src, const int* __restrict__ dst,
                          const float* __restrict__ dinv, int* __restrict__ cursor,
                          int2* __restrict__ csr) {
    int e = blockIdx.x * blockDim.x + threadIdx.x;
    if (e >= E) return;
    int s = src[e], d = dst[e];
    int slot = atomicAdd(&cursor[d], 1);
    float w = dinv[s] * dinv[d];
    csr[slot] = make_int2(s, __float_as_int(w));
}

// out[i] = (BIAS? b : 0) + dinv[i]^2*tbl[i] + sum_e w_e * tbl[src_e]
// one wave per node, lane = feature; 8-deep pipelined gathers + masked tail
template <bool BIAS>
__global__ __launch_bounds__(256) void k_agg(const float* __restrict__ tbl,
                                             const int* __restrict__ rp,
                                             const int2* __restrict__ csr,
                                             const float* __restrict__ dinv,
                                             const float* __restrict__ bias,
                                             float* __restrict__ outb) {
    int wv = threadIdx.x >> 6, lane = threadIdx.x & 63;
    int node = blockIdx.x * 4 + wv;
    if (node >= N) return;
    int beg = rp[node], end = rp[node + 1];
    float di   = dinv[node];
    float self = tbl[(size_t)node * 64 + lane];   // in flight early
    float a0 = 0.f, a1 = 0.f, a2 = 0.f, a3 = 0.f,
          a4 = 0.f, a5 = 0.f, a6 = 0.f, a7 = 0.f;
    int e = beg;
    int stop = beg + ((end - beg) & ~7);
    for (; e < stop; e += 8) {
        int2 c0 = csr[e + 0], c1 = csr[e + 1], c2 = csr[e + 2], c3 = csr[e + 3],
             c4 = csr[e + 4], c5 = csr[e + 5], c6 = csr[e + 6], c7 = csr[e + 7];
        float v0 = tbl[(size_t)c0.x * 64 + lane];
        float v1 = tbl[(size_t)c1.x * 64 + lane];
        float v2 = tbl[(size_t)c2.x * 64 + lane];
        float v3 = tbl[(size_t)c3.x * 64 + lane];
        float v4 = tbl[(size_t)c4.x * 64 + lane];
        float v5 = tbl[(size_t)c5.x * 64 + lane];
        float v6 = tbl[(size_t)c6.x * 64 + lane];
        float v7 = tbl[(size_t)c7.x * 64 + lane];
        a0 += __int_as_float(c0.y) * v0;
        a1 += __int_as_float(c1.y) * v1;
        a2 += __int_as_float(c2.y) * v2;
        a3 += __int_as_float(c3.y) * v3;
        a4 += __int_as_float(c4.y) * v4;
        a5 += __int_as_float(c5.y) * v5;
        a6 += __int_as_float(c6.y) * v6;
        a7 += __int_as_float(c7.y) * v7;
    }
    if (e < end) {   // masked block of 8: clamped index, zeroed weight
        int last = end - 1;
        int2 c0 = csr[min(e + 0, last)], c1 = csr[min(e + 1, last)],
             c2 = csr[min(e + 2, last)], c3 = csr[min(e + 3, last)],
             c4 = csr[min(e + 4, last)], c5 = csr[min(e + 5, last)],
             c6 = csr[min(e + 6, last)], c7 = csr[min(e + 7, last)];
        float v0 = tbl[(size_t)c0.x * 64 + lane];
        float v1 = tbl[(size_t)c1.x * 64 + lane];
        float v2 = tbl[(size_t)c2.x * 64 + lane];
        float v3 = tbl[(size_t)c3.x * 64 + lane];
        float v4 = tbl[(size_t)c4.x * 64 + lane];
        float v5 = tbl[(size_t)c5.x * 64 + lane];
        float v6 = tbl[(size_t)c6.x * 64 + lane];
        float v7 = tbl[(size_t)c7.x * 64 + lane];
        a0 += (e + 0 < end ? __int_as_float(c0.y) : 0.f) * v0;
        a1 += (e + 1 < end ? __int_as_float(c1.y) : 0.f) * v1;
        a2 += (e + 2 < end ? __int_as_float(c2.y) : 0.f) * v2;
        a3 += (e + 3 < end ? __int_as_float(c3.y) : 0.f) * v3;
        a4 += (e + 4 < end ? __int_as_float(c4.y) : 0.f) * v4;
        a5 += (e + 5 < end ? __int_as_float(c5.y) : 0.f) * v5;
        a6 += (e + 6 < end ? __int_as_float(c6.y) : 0.f) * v6;
        a7 += (e + 7 < end ? __int_as_float(c7.y) : 0.f) * v7;
    }
    float acc = di * di * self + (((a0 + a1) + (a2 + a3)) + ((a4 + a5) + (a6 + a7)));
    if (BIAS) acc += bias[lane];
    outb[(size_t)node * 64 + lane] = acc;
}

// h1r = relu(xa @ W1 + b1); 64 nodes/block, 256 threads, reg-blocked 8x4
__global__ __launch_bounds__(256) void k_gemm1(const float* __restrict__ xa,
                                               const float* __restrict__ W1,
                                               const float* __restrict__ b1,
                                               float* __restrict__ h1r) {
    __shared__ float Ws[FIN * FMID];   // [k][c] 32KB
    __shared__ float Xs[64 * FIN];     // [r][k] 16KB
    int t = threadIdx.x;
    int n0 = blockIdx.x * 64;
    float4* Ws4 = (float4*)Ws;
    const float4* W14 = (const float4*)W1;
#pragma unroll
    for (int i = 0; i < 8; ++i) Ws4[t + i * 256] = W14[t + i * 256];
    float4* Xs4 = (float4*)Xs;
    const float4* xa4 = (const float4*)xa;
#pragma unroll
    for (int i = 0; i < 4; ++i) {
        int j = t + i * 256;
        int r = j >> 4, c4 = j & 15;
        int n = n0 + r;
        Xs4[j] = (n < N) ? xa4[(size_t)n * 16 + c4] : float4{0.f, 0.f, 0.f, 0.f};
    }
    __syncthreads();
    int colg = t & 31, rowi = t >> 5;     // cols 4*colg (128), rows rowi + 8*rr (64)
    float acc[8][4];
#pragma unroll
    for (int a = 0; a < 8; ++a)
#pragma unroll
        for (int b = 0; b < 4; ++b) acc[a][b] = 0.f;
#pragma unroll 4
    for (int k = 0; k < FIN; ++k) {
        float4 w = ((float4*)(Ws + k * FMID))[colg];
#pragma unroll
        for (int rr = 0; rr < 8; ++rr) {
            float xv = Xs[(rowi + rr * 8) * FIN + k];
            acc[rr][0] += xv * w.x;
            acc[rr][1] += xv * w.y;
            acc[rr][2] += xv * w.z;
            acc[rr][3] += xv * w.w;
        }
    }
    float4 bb = ((const float4*)b1)[colg];
#pragma unroll
    for (int rr = 0; rr < 8; ++rr) {
        int n = n0 + rowi + rr * 8;
        if (n < N) {
            float4 o;
            o.x = fmaxf(acc[rr][0] + bb.x, 0.f);
            o.y = fmaxf(acc[rr][1] + bb.y, 0.f);
            o.z = fmaxf(acc[rr][2] + bb.z, 0.f);
            o.w = fmaxf(acc[rr][3] + bb.w, 0.f);
            ((float4*)(h1r + (size_t)n * FMID))[colg] = o;
        }
    }
}

// h2 = h1r @ W2; 32 nodes/block, 256 threads, reg-blocked 2x4
__global__ __launch_bounds__(256) void k_gemm2(const float* __restrict__ h1r,
                                               const float* __restrict__ W2,
                                               float* __restrict__ h2) {
    __shared__ float Ws[FMID * FOUT];  // [k][c] 32KB
    __shared__ float Xs[32 * FMID];    // [r][k] 16KB
    int t = threadIdx.x;
    int n0 = blockIdx.x * 32;
    float4* Ws4 = (float4*)Ws;
    const float4* W24 = (const float4*)W2;
#pragma unroll
    for (int i = 0; i < 8; ++i) Ws4[t + i * 256] = W24[t + i * 256];
    float4* Xs4 = (float4*)Xs;
    const float4* h4 = (const float4*)h1r;
#pragma unroll
    for (int i = 0; i < 4; ++i) {
        int j = t + i * 256;
        int r = j >> 5, c4 = j & 31;
        int n = n0 + r;
        Xs4[j] = (n < N) ? h4[(size_t)n * 32 + c4] : float4{0.f, 0.f, 0.f, 0.f};
    }
    __syncthreads();
    int colg = t & 15, rowi = t >> 4;     // cols 4*colg (64), rows rowi + 16*rr (32)
    float acc[2][4];
#pragma unroll
    for (int a = 0; a < 2; ++a)
#pragma unroll
        for (int b = 0; b < 4; ++b) acc[a][b] = 0.f;
#pragma unroll 4
    for (int k = 0; k < FMID; ++k) {
        float4 w = ((float4*)(Ws + k * FOUT))[colg];
#pragma unroll
        for (int rr = 0; rr < 2; ++rr) {
            float xv = Xs[(rowi + rr * 16) * FMID + k];
            acc[rr][0] += xv * w.x;
            acc[rr][1] += xv * w.y;
            acc[rr][2] += xv * w.z;
            acc[rr][3] += xv * w.w;
        }
    }
#pragma unroll
    for (int rr = 0; rr < 2; ++rr) {
        int n = n0 + rowi + rr * 16;
        if (n < N) {
            float4 o = {acc[rr][0], acc[rr][1], acc[rr][2], acc[rr][3]};
            ((float4*)(h2 + (size_t)n * FOUT))[colg] = o;
        }
    }
}

// one block (4 waves) per graph; batch sorted -> binary search node range
__global__ __launch_bounds__(256) void k_pool(const float* __restrict__ o2,
                                              const int* __restrict__ batch,
                                              float* __restrict__ out) {
    __shared__ float red[256];
    int g = blockIdx.x;
    int wv = threadIdx.x >> 6, lane = threadIdx.x & 63;
    int lo = 0, hi = N;
    while (lo < hi) { int m = (lo + hi) >> 1; if (batch[m] < g) lo = m + 1; else hi = m; }
    int start = lo;
    hi = N;
    while (lo < hi) { int m = (lo + hi) >> 1; if (batch[m] < g + 1) lo = m + 1; else hi = m; }
    int end = lo;
    float acc = 0.f;
    for (int n = start + wv; n < end; n += 4) acc += o2[(size_t)n * FOUT + lane];
    red[threadIdx.x] = acc;
    __syncthreads();
    if (wv == 0) {
        float v = red[lane] + red[64 + lane] + red[128 + lane] + red[192 + lane];
        out[g * FOUT + lane] = v / fmaxf((float)(end - start), 1.f);
    }
}

extern "C" void kernel_launch(void* const* d_in, const int* in_sizes, int n_in,
                              void* d_out, int out_size, void* d_ws, size_t ws_size,
                              hipStream_t stream) {
    const float* x     = (const float*)d_in[0];
    const int*   ei    = (const int*)d_in[1];
    const int*   batch = (const int*)d_in[2];
    const float* W1    = (const float*)d_in[3];
    const float* b1    = (const float*)d_in[4];
    const float* W2    = (const float*)d_in[5];
    const float* b2    = (const float*)d_in[6];
    float* out = (float*)d_out;

    const int* srcp = ei;        // edge_index[0]
    const int* dstp = ei + E;    // edge_index[1]

    char* ws = (char*)d_ws;
    int*   edeg    = (int*)  (ws + 0);          //   200,000 -> 200,704
    int*   cursor  = (int*)  (ws + 200704);     //   200,000 -> 401,408
    float* dinv    = (float*)(ws + 401408);     //   200,000 -> 602,112
    int*   row_ptr = (int*)  (ws + 602112);     //   200,004 -> 802,816
    int*   bsum    = (int*)  (ws + 802816);     //       256 -> 803,328
    int2*  csr     = (int2*) (ws + 803328);     // 6,400,000 -> 7,203,328
    float* xa      = (float*)(ws + 7203328);    // 12,800,000 -> 20,003,328
    float* h1r     = (float*)(ws + 20003328);   // 25,600,000 -> 45,603,328
    // lifetimes: xa dead after gemm1 -> h2 aliases xa; h1r dead after gemm2 -> o2 aliases h1r
    float* h2 = xa;
    float* o2 = h1r;

    dim3 B(256);

    k_zero_edeg<<<dim3((N + 255) / 256), B, 0, stream>>>(edeg);
    k_deg<<<dim3((E + 255) / 256), B, 0, stream>>>(dstp, edeg);
    k_scan1<<<dim3(NB_SCAN), B, 0, stream>>>(edeg, row_ptr, bsum);
    k_scan2<<<dim3(1), dim3(64), 0, stream>>>(bsum);
    k_scan3<<<dim3((N + 255) / 256), B, 0, stream>>>(edeg, row_ptr, bsum, cursor, dinv);
    k_scatter<<<dim3((E + 255) / 256), B, 0, stream>>>(srcp, dstp, dinv, cursor, csr);

    k_agg<false><<<dim3((N + 3) / 4), B, 0, stream>>>(x, row_ptr, csr, dinv, nullptr, xa);
    k_gemm1<<<dim3((N + 63) / 64), B, 0, stream>>>(xa, W1, b1, h1r);
    k_gemm2<<<dim3((N + 31) / 32), B, 0, stream>>>(h1r, W2, h2);
    k_agg<true><<<dim3((N + 3) / 4), B, 0, stream>>>(h2, row_ptr, csr, dinv, b2, o2);
    k_pool<<<dim3(G), B, 0, stream>>>(o2, batch, out);
}

// Round 5
// 200.110 us; speedup vs baseline: 11.5281x; 1.0686x over previous
//
#include <hip/hip_runtime.h>

constexpr int N    = 50000;
constexpr int E    = 800000;
constexpr int FIN  = 64;
constexpr int FMID = 128;
constexpr int FOUT = 64;
constexpr int G    = 512;
constexpr int SCAN_ITEMS = 1024;
constexpr int NB_SCAN = (N + SCAN_ITEMS - 1) / SCAN_ITEMS;   // 49

// degree + per-edge rank capture (rank store is sequential)
__global__ void k_deg(const int* __restrict__ dst, int* __restrict__ edeg,
                      int* __restrict__ rank) {
    int e = blockIdx.x * blockDim.x + threadIdx.x;
    if (e < E) rank[e] = atomicAdd(&edeg[dst[e]], 1);
}

// block-level exclusive scan of edeg (1024 items / block)
__global__ __launch_bounds__(256) void k_scan1(const int* __restrict__ edeg,
                                               int* __restrict__ row_ptr,
                                               int* __restrict__ bsum) {
    __shared__ int s[256];
    int t = threadIdx.x;
    int base = blockIdx.x * SCAN_ITEMS + t * 4;
    int v0 = (base + 0 < N) ? edeg[base + 0] : 0;
    int v1 = (base + 1 < N) ? edeg[base + 1] : 0;
    int v2 = (base + 2 < N) ? edeg[base + 2] : 0;
    int v3 = (base + 3 < N) ? edeg[base + 3] : 0;
    int tsum = v0 + v1 + v2 + v3;
    s[t] = tsum;
    __syncthreads();
    for (int off = 1; off < 256; off <<= 1) {
        int add = (t >= off) ? s[t - off] : 0;
        __syncthreads();
        s[t] += add;
        __syncthreads();
    }
    int texcl = s[t] - tsum;
    if (t == 255) bsum[blockIdx.x] = s[255];
    if (base + 0 < N) row_ptr[base + 0] = texcl;
    if (base + 1 < N) row_ptr[base + 1] = texcl + v0;
    if (base + 2 < N) row_ptr[base + 2] = texcl + v0 + v1;
    if (base + 3 < N) row_ptr[base + 3] = texcl + v0 + v1 + v2;
}

__global__ void k_scan2(int* __restrict__ bsum) {
    if (threadIdx.x == 0 && blockIdx.x == 0) {
        int run = 0;
        for (int b = 0; b < NB_SCAN; ++b) { int v = bsum[b]; bsum[b] = run; run += v; }
    }
}

// finalize row_ptr, dinv, and build xd = dinv ⊙ x  (one wave per node)
__global__ __launch_bounds__(256) void k_scan3x(const int* __restrict__ edeg,
                                                int* __restrict__ row_ptr,
                                                const int* __restrict__ bsum,
                                                float* __restrict__ dinv,
                                                const float* __restrict__ x,
                                                float* __restrict__ xd) {
    int wv = threadIdx.x >> 6, lane = threadIdx.x & 63;
    int i = blockIdx.x * 4 + wv;
    if (i >= N) return;
    int rp = row_ptr[i] + bsum[i >> 10];           // SCAN_ITEMS = 1024
    float di = rsqrtf(1.0f + (float)edeg[i]);
    if (lane == 0) {
        row_ptr[i] = rp;
        dinv[i] = di;
        if (i == 0) row_ptr[N] = E;
    }
    xd[(size_t)i * 64 + lane] = di * x[(size_t)i * 64 + lane];
}

// non-atomic scatter: slot = row_ptr[dst] + rank
__global__ void k_scatter(const int* __restrict__ src, const int* __restrict__ dst,
                          const int* __restrict__ rank, const int* __restrict__ row_ptr,
                          int* __restrict__ csr) {
    int e = blockIdx.x * blockDim.x + threadIdx.x;
    if (e >= E) return;
    csr[row_ptr[dst[e]] + rank[e]] = src[e];
}

// out[i] = (BIAS? b : 0) + dinv[i] * ( tbl[i] + sum_e tbl[csr_e] )
// one wave per node, lane = feature; 16-deep pipelined gathers + masked tail
template <bool BIAS>
__global__ __launch_bounds__(256) void k_agg(const float* __restrict__ tbl,
                                             const int* __restrict__ rp,
                                             const int* __restrict__ csr,
                                             const float* __restrict__ dinv,
                                             const float* __restrict__ bias,
                                             float* __restrict__ outb) {
    int wv = threadIdx.x >> 6, lane = threadIdx.x & 63;
    int node = blockIdx.x * 4 + wv;
    if (node >= N) return;
    int beg = rp[node], end = rp[node + 1];
    float self = tbl[(size_t)node * 64 + lane];
    float a[8];
#pragma unroll
    for (int j = 0; j < 8; ++j) a[j] = 0.f;
    int e = beg;
    int stop = beg + ((end - beg) & ~15);
    for (; e < stop; e += 16) {
        int s[16];
#pragma unroll
        for (int j = 0; j < 16; ++j) s[j] = csr[e + j];
        float v[16];
#pragma unroll
        for (int j = 0; j < 16; ++j) v[j] = tbl[(size_t)s[j] * 64 + lane];
#pragma unroll
        for (int j = 0; j < 16; ++j) a[j & 7] += v[j];
    }
    if (e < end) {   // masked block of 16: clamped index, cndmask'd value
        int last = end - 1;
        int s[16];
#pragma unroll
        for (int j = 0; j < 16; ++j) s[j] = csr[min(e + j, last)];
        float v[16];
#pragma unroll
        for (int j = 0; j < 16; ++j) v[j] = tbl[(size_t)s[j] * 64 + lane];
#pragma unroll
        for (int j = 0; j < 16; ++j) a[j & 7] += (e + j < end) ? v[j] : 0.f;
    }
    float sum = self + (((a[0] + a[1]) + (a[2] + a[3])) + ((a[4] + a[5]) + (a[6] + a[7])));
    float res = dinv[node] * sum;
    if (BIAS) res += bias[lane];
    outb[(size_t)node * 64 + lane] = res;
}

// fused: h2d = dinv ⊙ ( relu(xa @ W1 + b1) @ W2 );  64 nodes / 256-thread block
// LDS 64KB: phase A {W1[64*128] | Xs[64*64]} -> phase B {H1 swizzled [128][64] | W2[128*64]}
__global__ __launch_bounds__(256) void k_gemm_fused(const float* __restrict__ xa,
                                                    const float* __restrict__ W1,
                                                    const float* __restrict__ b1,
                                                    const float* __restrict__ W2,
                                                    const float* __restrict__ dinv,
                                                    float* __restrict__ h2d) {
    __shared__ float sm[16384];         // 64 KB exactly
    float* Ws1 = sm;                    // phase A: [64k][128c]
    float4* Xs4 = (float4*)(sm + 8192); // phase A: [64r][16 float4]
    float* H1  = sm;                    // phase B: swizzled [128k][64r]
    float* Ws2 = sm + 8192;             // phase B: [128k][64c]
    int t = threadIdx.x;
    int n0 = blockIdx.x * 64;

    // prefetch W2 into registers (consumed after phase A)
    const float4* W24 = (const float4*)W2;
    float4 w2r[8];
#pragma unroll
    for (int i = 0; i < 8; ++i) w2r[i] = W24[t + i * 256];

    // stage W1 + Xs
    float4* sm4 = (float4*)sm;
    const float4* W14 = (const float4*)W1;
#pragma unroll
    for (int i = 0; i < 8; ++i) sm4[t + i * 256] = W14[t + i * 256];
    const float4* xa4 = (const float4*)xa;
#pragma unroll
    for (int i = 0; i < 4; ++i) {
        int j = t + i * 256;
        int r = j >> 4, c4 = j & 15;
        int n = n0 + r;
        Xs4[j] = (n < N) ? xa4[(size_t)n * 16 + c4] : float4{0.f, 0.f, 0.f, 0.f};
    }
    __syncthreads();

    // phase A: acc[rr][c] for rows rowi+8rr, cols 4colg+c (of 128)
    int colg = t & 31, rowi = t >> 5;
    float acc[8][4] = {};
#pragma unroll
    for (int k4 = 0; k4 < 16; ++k4) {
        float4 w0 = ((float4*)(Ws1 + (4 * k4 + 0) * FMID))[colg];
        float4 w1 = ((float4*)(Ws1 + (4 * k4 + 1) * FMID))[colg];
        float4 w2 = ((float4*)(Ws1 + (4 * k4 + 2) * FMID))[colg];
        float4 w3 = ((float4*)(Ws1 + (4 * k4 + 3) * FMID))[colg];
#pragma unroll
        for (int rr = 0; rr < 8; ++rr) {
            float4 xv = Xs4[(rowi + rr * 8) * 16 + k4];
            acc[rr][0] += xv.x * w0.x + xv.y * w1.x + xv.z * w2.x + xv.w * w3.x;
            acc[rr][1] += xv.x * w0.y + xv.y * w1.y + xv.z * w2.y + xv.w * w3.y;
            acc[rr][2] += xv.x * w0.z + xv.y * w1.z + xv.z * w2.z + xv.w * w3.z;
            acc[rr][3] += xv.x * w0.w + xv.y * w1.w + xv.z * w2.w + xv.w * w3.w;
        }
    }
    float4 bb = ((const float4*)b1)[colg];
    __syncthreads();   // all reads of Ws1/Xs done -> safe to overwrite

    // write relu(h1+b1) into H1 swizzled: addr = col*64 + ((row+col)&63)
#pragma unroll
    for (int rr = 0; rr < 8; ++rr) {
        int row = rowi + rr * 8;
        int c0 = 4 * colg;
        H1[(c0 + 0) * 64 + ((row + c0 + 0) & 63)] = fmaxf(acc[rr][0] + bb.x, 0.f);
        H1[(c0 + 1) * 64 + ((row + c0 + 1) & 63)] = fmaxf(acc[rr][1] + bb.y, 0.f);
        H1[(c0 + 2) * 64 + ((row + c0 + 2) & 63)] = fmaxf(acc[rr][2] + bb.z, 0.f);
        H1[(c0 + 3) * 64 + ((row + c0 + 3) & 63)] = fmaxf(acc[rr][3] + bb.w, 0.f);
    }
    // stage W2 from the prefetch registers
    float4* Ws24 = (float4*)Ws2;
#pragma unroll
    for (int i = 0; i < 8; ++i) Ws24[t + i * 256] = w2r[i];
    __syncthreads();

    // phase B: rows rowi2+16rr (64), cols 4colg2+c (of 64)
    int colg2 = t & 15, rowi2 = t >> 4;
    float acc2[4][4] = {};
    for (int k = 0; k < FMID; ++k) {
        float4 w = ((float4*)(Ws2 + k * FOUT))[colg2];
#pragma unroll
        for (int rr = 0; rr < 4; ++rr) {
            int row = rowi2 + 16 * rr;
            float xv = H1[k * 64 + ((row + k) & 63)];
            acc2[rr][0] += xv * w.x;
            acc2[rr][1] += xv * w.y;
            acc2[rr][2] += xv * w.z;
            acc2[rr][3] += xv * w.w;
        }
    }
#pragma unroll
    for (int rr = 0; rr < 4; ++rr) {
        int n = n0 + rowi2 + 16 * rr;
        if (n < N) {
            float di = dinv[n];
            float4 o = {di * acc2[rr][0], di * acc2[rr][1],
                        di * acc2[rr][2], di * acc2[rr][3]};
            ((float4*)(h2d + (size_t)n * FOUT))[colg2] = o;
        }
    }
}

// one block (4 waves) per graph; batch sorted -> binary search node range
__global__ __launch_bounds__(256) void k_pool(const float* __restrict__ o2,
                                              const int* __restrict__ batch,
                                              float* __restrict__ out) {
    __shared__ float red[256];
    int g = blockIdx.x;
    int wv = threadIdx.x >> 6, lane = threadIdx.x & 63;
    int lo = 0, hi = N;
    while (lo < hi) { int m = (lo + hi) >> 1; if (batch[m] < g) lo = m + 1; else hi = m; }
    int start = lo;
    hi = N;
    while (lo < hi) { int m = (lo + hi) >> 1; if (batch[m] < g + 1) lo = m + 1; else hi = m; }
    int end = lo;
    float acc = 0.f;
    for (int n = start + wv; n < end; n += 4) acc += o2[(size_t)n * FOUT + lane];
    red[threadIdx.x] = acc;
    __syncthreads();
    if (wv == 0) {
        float v = red[lane] + red[64 + lane] + red[128 + lane] + red[192 + lane];
        out[g * FOUT + lane] = v / fmaxf((float)(end - start), 1.f);
    }
}

extern "C" void kernel_launch(void* const* d_in, const int* in_sizes, int n_in,
                              void* d_out, int out_size, void* d_ws, size_t ws_size,
                              hipStream_t stream) {
    const float* x     = (const float*)d_in[0];
    const int*   ei    = (const int*)d_in[1];
    const int*   batch = (const int*)d_in[2];
    const float* W1    = (const float*)d_in[3];
    const float* b1    = (const float*)d_in[4];
    const float* W2    = (const float*)d_in[5];
    const float* b2    = (const float*)d_in[6];
    float* out = (float*)d_out;

    const int* srcp = ei;        // edge_index[0]
    const int* dstp = ei + E;    // edge_index[1]

    char* ws = (char*)d_ws;
    int*   edeg    = (int*)  (ws + 0);          //   200,000 -> 200,704
    int*   rank    = (int*)  (ws + 200704);     // 3,200,000 -> 3,400,704
    float* dinv    = (float*)(ws + 3400704);    //   200,000 -> 3,601,408
    int*   row_ptr = (int*)  (ws + 3601408);    //   200,004 -> 3,802,112
    int*   bsum    = (int*)  (ws + 3802112);    //       256 -> 3,802,624
    int*   csr     = (int*)  (ws + 3802624);    // 3,200,000 -> 7,002,624
    float* xd      = (float*)(ws + 7002624);    // 12,800,000 -> 19,802,624
    float* xa      = (float*)(ws + 19802624);   // 12,800,000 -> 32,602,624
    float* h2d     = (float*)(ws + 32602624);   // 12,800,000 -> 45,402,624
    float* o2      = xa;                        // xa dead after gemm_fused

    dim3 B(256);

    hipMemsetAsync(edeg, 0, N * sizeof(int), stream);
    k_deg<<<dim3((E + 255) / 256), B, 0, stream>>>(dstp, edeg, rank);
    k_scan1<<<dim3(NB_SCAN), B, 0, stream>>>(edeg, row_ptr, bsum);
    k_scan2<<<dim3(1), dim3(64), 0, stream>>>(bsum);
    k_scan3x<<<dim3((N + 3) / 4), B, 0, stream>>>(edeg, row_ptr, bsum, dinv, x, xd);
    k_scatter<<<dim3((E + 255) / 256), B, 0, stream>>>(srcp, dstp, rank, row_ptr, csr);

    k_agg<false><<<dim3((N + 3) / 4), B, 0, stream>>>(xd, row_ptr, csr, dinv, nullptr, xa);
    k_gemm_fused<<<dim3((N + 63) / 64), B, 0, stream>>>(xa, W1, b1, W2, dinv, h2d);
    k_agg<true><<<dim3((N + 3) / 4), B, 0, stream>>>(h2d, row_ptr, csr, dinv, b2, o2);
    k_pool<<<dim3(G), B, 0, stream>>>(o2, batch, out);
}

// Round 6
// 189.821 us; speedup vs baseline: 12.1530x; 1.0542x over previous
//
#include <hip/hip_runtime.h>

constexpr int N    = 50000;
constexpr int E    = 800000;
constexpr int FIN  = 64;
constexpr int FMID = 128;
constexpr int FOUT = 64;
constexpr int G    = 512;
constexpr int SCAN_ITEMS = 1024;
constexpr int NB_SCAN = (N + SCAN_ITEMS - 1) / SCAN_ITEMS;   // 49

// degree + per-edge rank capture (rank store is sequential)
__global__ void k_deg(const int* __restrict__ dst, int* __restrict__ edeg,
                      int* __restrict__ rank) {
    int e = blockIdx.x * blockDim.x + threadIdx.x;
    if (e < E) rank[e] = atomicAdd(&edeg[dst[e]], 1);
}

// block-level exclusive scan of edeg (1024 items / block)
__global__ __launch_bounds__(256) void k_scan1(const int* __restrict__ edeg,
                                               int* __restrict__ row_ptr,
                                               int* __restrict__ bsum) {
    __shared__ int s[256];
    int t = threadIdx.x;
    int base = blockIdx.x * SCAN_ITEMS + t * 4;
    int v0 = (base + 0 < N) ? edeg[base + 0] : 0;
    int v1 = (base + 1 < N) ? edeg[base + 1] : 0;
    int v2 = (base + 2 < N) ? edeg[base + 2] : 0;
    int v3 = (base + 3 < N) ? edeg[base + 3] : 0;
    int tsum = v0 + v1 + v2 + v3;
    s[t] = tsum;
    __syncthreads();
    for (int off = 1; off < 256; off <<= 1) {
        int add = (t >= off) ? s[t - off] : 0;
        __syncthreads();
        s[t] += add;
        __syncthreads();
    }
    int texcl = s[t] - tsum;
    if (t == 255) bsum[blockIdx.x] = s[255];
    if (base + 0 < N) row_ptr[base + 0] = texcl;
    if (base + 1 < N) row_ptr[base + 1] = texcl + v0;
    if (base + 2 < N) row_ptr[base + 2] = texcl + v0 + v1;
    if (base + 3 < N) row_ptr[base + 3] = texcl + v0 + v1 + v2;
}

__global__ void k_scan2(int* __restrict__ bsum) {
    if (threadIdx.x == 0 && blockIdx.x == 0) {
        int run = 0;
        for (int b = 0; b < NB_SCAN; ++b) { int v = bsum[b]; bsum[b] = run; run += v; }
    }
}

// finalize row_ptr, dinv, and build xd = dinv ⊙ x  (one wave per node)
__global__ __launch_bounds__(256) void k_scan3x(const int* __restrict__ edeg,
                                                int* __restrict__ row_ptr,
                                                const int* __restrict__ bsum,
                                                float* __restrict__ dinv,
                                                const float* __restrict__ x,
                                                float* __restrict__ xd) {
    int wv = threadIdx.x >> 6, lane = threadIdx.x & 63;
    int i = blockIdx.x * 4 + wv;
    if (i >= N) return;
    int rp = row_ptr[i] + bsum[i >> 10];           // SCAN_ITEMS = 1024
    float di = rsqrtf(1.0f + (float)edeg[i]);
    if (lane == 0) {
        row_ptr[i] = rp;
        dinv[i] = di;
        if (i == 0) row_ptr[N] = E;
    }
    xd[(size_t)i * 64 + lane] = di * x[(size_t)i * 64 + lane];
}

// non-atomic scatter: slot = row_ptr[dst] + rank
__global__ void k_scatter(const int* __restrict__ src, const int* __restrict__ dst,
                          const int* __restrict__ rank, const int* __restrict__ row_ptr,
                          int* __restrict__ csr) {
    int e = blockIdx.x * blockDim.x + threadIdx.x;
    if (e >= E) return;
    csr[row_ptr[dst[e]] + rank[e]] = src[e];
}

// out[i] = (BIAS? b : 0) + dinv[i] * ( tbl[i] + sum_e tbl[csr_e] )
// one wave per node, lane = feature; 16-deep pipelined gathers + masked tail
template <bool BIAS>
__global__ __launch_bounds__(256) void k_agg(const float* __restrict__ tbl,
                                             const int* __restrict__ rp,
                                             const int* __restrict__ csr,
                                             const float* __restrict__ dinv,
                                             const float* __restrict__ bias,
                                             float* __restrict__ outb) {
    int wv = threadIdx.x >> 6, lane = threadIdx.x & 63;
    int node = blockIdx.x * 4 + wv;
    if (node >= N) return;
    int beg = rp[node], end = rp[node + 1];
    float self = tbl[(size_t)node * 64 + lane];
    float a[8];
#pragma unroll
    for (int j = 0; j < 8; ++j) a[j] = 0.f;
    int e = beg;
    int stop = beg + ((end - beg) & ~15);
    for (; e < stop; e += 16) {
        int s[16];
#pragma unroll
        for (int j = 0; j < 16; ++j) s[j] = csr[e + j];
        float v[16];
#pragma unroll
        for (int j = 0; j < 16; ++j) v[j] = tbl[(size_t)s[j] * 64 + lane];
#pragma unroll
        for (int j = 0; j < 16; ++j) a[j & 7] += v[j];
    }
    if (e < end) {   // masked block of 16: clamped index, cndmask'd value
        int last = end - 1;
        int s[16];
#pragma unroll
        for (int j = 0; j < 16; ++j) s[j] = csr[min(e + j, last)];
        float v[16];
#pragma unroll
        for (int j = 0; j < 16; ++j) v[j] = tbl[(size_t)s[j] * 64 + lane];
#pragma unroll
        for (int j = 0; j < 16; ++j) a[j & 7] += (e + j < end) ? v[j] : 0.f;
    }
    float sum = self + (((a[0] + a[1]) + (a[2] + a[3])) + ((a[4] + a[5]) + (a[6] + a[7])));
    float res = dinv[node] * sum;
    if (BIAS) res += bias[lane];
    outb[(size_t)node * 64 + lane] = res;
}

// fused: h2d = dinv ⊙ ( relu(xa @ W1 + b1) @ W2 );  64 nodes / 256-thread block
// LDS 48KB (3 blocks/CU): phase A {W1[64x128] 32KB | Xs[64x64] 16KB}
//                      -> phase B {H1 swizzled 32KB | W2 streamed in 2x16KB halves}
__global__ __launch_bounds__(256) void k_gemm_fused(const float* __restrict__ xa,
                                                    const float* __restrict__ W1,
                                                    const float* __restrict__ b1,
                                                    const float* __restrict__ W2,
                                                    const float* __restrict__ dinv,
                                                    float* __restrict__ h2d) {
    __shared__ float sm[12288];         // 48 KB
    float* Ws1 = sm;                    // phase A: [64k][128c]
    float4* Xs4 = (float4*)(sm + 8192); // phase A: [64r][16 float4]
    float* H1  = sm;                    // phase B: swizzled [128k][64r]
    float* Ws2 = sm + 8192;             // phase B: [64k][64c] per half
    int t = threadIdx.x;
    int n0 = blockIdx.x * 64;

    // stage W1 + Xs
    float4* sm4 = (float4*)sm;
    const float4* W14 = (const float4*)W1;
#pragma unroll
    for (int i = 0; i < 8; ++i) sm4[t + i * 256] = W14[t + i * 256];
    const float4* xa4 = (const float4*)xa;
#pragma unroll
    for (int i = 0; i < 4; ++i) {
        int j = t + i * 256;
        int r = j >> 4, c4 = j & 15;
        int n = n0 + r;
        Xs4[j] = (n < N) ? xa4[(size_t)n * 16 + c4] : float4{0.f, 0.f, 0.f, 0.f};
    }
    __syncthreads();

    // phase A: acc[rr][c] for rows rowi+8rr, cols 4colg+c (of 128)
    int colg = t & 31, rowi = t >> 5;
    float acc[8][4] = {};
#pragma unroll
    for (int k4 = 0; k4 < 16; ++k4) {
        float4 w0 = ((float4*)(Ws1 + (4 * k4 + 0) * FMID))[colg];
        float4 w1 = ((float4*)(Ws1 + (4 * k4 + 1) * FMID))[colg];
        float4 w2 = ((float4*)(Ws1 + (4 * k4 + 2) * FMID))[colg];
        float4 w3 = ((float4*)(Ws1 + (4 * k4 + 3) * FMID))[colg];
#pragma unroll
        for (int rr = 0; rr < 8; ++rr) {
            float4 xv = Xs4[(rowi + rr * 8) * 16 + k4];
            acc[rr][0] += xv.x * w0.x + xv.y * w1.x + xv.z * w2.x + xv.w * w3.x;
            acc[rr][1] += xv.x * w0.y + xv.y * w1.y + xv.z * w2.y + xv.w * w3.y;
            acc[rr][2] += xv.x * w0.z + xv.y * w1.z + xv.z * w2.z + xv.w * w3.z;
            acc[rr][3] += xv.x * w0.w + xv.y * w1.w + xv.z * w2.w + xv.w * w3.w;
        }
    }
    float4 bb = ((const float4*)b1)[colg];
    __syncthreads();   // all reads of Ws1/Xs done -> safe to overwrite

    // write relu(h1+b1) into H1, swizzle addr = k*64 + ((row + (k>>2)) & 63)
    // (k>>2) == colg for k = 4*colg+i -> write banks (row+colg)&31: conflict-free
#pragma unroll
    for (int rr = 0; rr < 8; ++rr) {
        int row = rowi + rr * 8;
        int k0 = 4 * colg;
        H1[(k0 + 0) * 64 + ((row + colg) & 63)] = fmaxf(acc[rr][0] + bb.x, 0.f);
        H1[(k0 + 1) * 64 + ((row + colg) & 63)] = fmaxf(acc[rr][1] + bb.y, 0.f);
        H1[(k0 + 2) * 64 + ((row + colg) & 63)] = fmaxf(acc[rr][2] + bb.z, 0.f);
        H1[(k0 + 3) * 64 + ((row + colg) & 63)] = fmaxf(acc[rr][3] + bb.w, 0.f);
    }
    // stage W2 rows 0..63 (16KB) into dead Xs region
    float4* Ws24 = (float4*)Ws2;
    const float4* W24 = (const float4*)W2;
#pragma unroll
    for (int i = 0; i < 4; ++i) Ws24[t + i * 256] = W24[t + i * 256];
    __syncthreads();

    // phase B: rows rowi2+16rr (64), cols 4colg2+c (of 64)
    int colg2 = t & 15, rowi2 = t >> 4;
    float acc2[4][4] = {};
#pragma unroll 4
    for (int k = 0; k < 64; ++k) {
        float4 w = ((float4*)(Ws2 + k * FOUT))[colg2];
        int ks = k >> 2;
#pragma unroll
        for (int rr = 0; rr < 4; ++rr) {
            int row = rowi2 + 16 * rr;
            float xv = H1[k * 64 + ((row + ks) & 63)];
            acc2[rr][0] += xv * w.x;
            acc2[rr][1] += xv * w.y;
            acc2[rr][2] += xv * w.z;
            acc2[rr][3] += xv * w.w;
        }
    }
    __syncthreads();
    // stage W2 rows 64..127
#pragma unroll
    for (int i = 0; i < 4; ++i) Ws24[t + i * 256] = W24[1024 + t + i * 256];
    __syncthreads();
#pragma unroll 4
    for (int k = 64; k < 128; ++k) {
        float4 w = ((float4*)(Ws2 + (k - 64) * FOUT))[colg2];
        int ks = k >> 2;
#pragma unroll
        for (int rr = 0; rr < 4; ++rr) {
            int row = rowi2 + 16 * rr;
            float xv = H1[k * 64 + ((row + ks) & 63)];
            acc2[rr][0] += xv * w.x;
            acc2[rr][1] += xv * w.y;
            acc2[rr][2] += xv * w.z;
            acc2[rr][3] += xv * w.w;
        }
    }
#pragma unroll
    for (int rr = 0; rr < 4; ++rr) {
        int n = n0 + rowi2 + 16 * rr;
        if (n < N) {
            float di = dinv[n];
            float4 o = {di * acc2[rr][0], di * acc2[rr][1],
                        di * acc2[rr][2], di * acc2[rr][3]};
            ((float4*)(h2d + (size_t)n * FOUT))[colg2] = o;
        }
    }
}

// one block (4 waves) per graph; batch sorted -> binary search node range
__global__ __launch_bounds__(256) void k_pool(const float* __restrict__ o2,
                                              const int* __restrict__ batch,
                                              float* __restrict__ out) {
    __shared__ float red[256];
    int g = blockIdx.x;
    int wv = threadIdx.x >> 6, lane = threadIdx.x & 63;
    int lo = 0, hi = N;
    while (lo < hi) { int m = (lo + hi) >> 1; if (batch[m] < g) lo = m + 1; else hi = m; }
    int start = lo;
    hi = N;
    while (lo < hi) { int m = (lo + hi) >> 1; if (batch[m] < g + 1) lo = m + 1; else hi = m; }
    int end = lo;
    float acc = 0.f;
    for (int n = start + wv; n < end; n += 4) acc += o2[(size_t)n * FOUT + lane];
    red[threadIdx.x] = acc;
    __syncthreads();
    if (wv == 0) {
        float v = red[lane] + red[64 + lane] + red[128 + lane] + red[192 + lane];
        out[g * FOUT + lane] = v / fmaxf((float)(end - start), 1.f);
    }
}

extern "C" void kernel_launch(void* const* d_in, const int* in_sizes, int n_in,
                              void* d_out, int out_size, void* d_ws, size_t ws_size,
                              hipStream_t stream) {
    const float* x     = (const float*)d_in[0];
    const int*   ei    = (const int*)d_in[1];
    const int*   batch = (const int*)d_in[2];
    const float* W1    = (const float*)d_in[3];
    const float* b1    = (const float*)d_in[4];
    const float* W2    = (const float*)d_in[5];
    const float* b2    = (const float*)d_in[6];
    float* out = (float*)d_out;

    const int* srcp = ei;        // edge_index[0]
    const int* dstp = ei + E;    // edge_index[1]

    char* ws = (char*)d_ws;
    int*   edeg    = (int*)  (ws + 0);          //   200,000 -> 200,704
    int*   rank    = (int*)  (ws + 200704);     // 3,200,000 -> 3,400,704
    float* dinv    = (float*)(ws + 3400704);    //   200,000 -> 3,601,408
    int*   row_ptr = (int*)  (ws + 3601408);    //   200,004 -> 3,802,112
    int*   bsum    = (int*)  (ws + 3802112);    //       256 -> 3,802,624
    int*   csr     = (int*)  (ws + 3802624);    // 3,200,000 -> 7,002,624
    float* xd      = (float*)(ws + 7002624);    // 12,800,000 -> 19,802,624
    float* xa      = (float*)(ws + 19802624);   // 12,800,000 -> 32,602,624
    float* h2d     = (float*)(ws + 32602624);   // 12,800,000 -> 45,402,624
    float* o2      = xa;                        // xa dead after gemm_fused

    dim3 B(256);

    hipMemsetAsync(edeg, 0, N * sizeof(int), stream);
    k_deg<<<dim3((E + 255) / 256), B, 0, stream>>>(dstp, edeg, rank);
    k_scan1<<<dim3(NB_SCAN), B, 0, stream>>>(edeg, row_ptr, bsum);
    k_scan2<<<dim3(1), dim3(64), 0, stream>>>(bsum);
    k_scan3x<<<dim3((N + 3) / 4), B, 0, stream>>>(edeg, row_ptr, bsum, dinv, x, xd);
    k_scatter<<<dim3((E + 255) / 256), B, 0, stream>>>(srcp, dstp, rank, row_ptr, csr);

    k_agg<false><<<dim3((N + 3) / 4), B, 0, stream>>>(xd, row_ptr, csr, dinv, nullptr, xa);
    k_gemm_fused<<<dim3((N + 63) / 64), B, 0, stream>>>(xa, W1, b1, W2, dinv, h2d);
    k_agg<true><<<dim3((N + 3) / 4), B, 0, stream>>>(h2d, row_ptr, csr, dinv, b2, o2);
    k_pool<<<dim3(G), B, 0, stream>>>(o2, batch, out);
}

// Round 7
// 173.224 us; speedup vs baseline: 13.3174x; 1.0958x over previous
//
#include <hip/hip_runtime.h>

typedef unsigned short ushort_t;
typedef unsigned int uint_t;

constexpr int N    = 50000;
constexpr int E    = 800000;
constexpr int FIN  = 64;
constexpr int FMID = 128;
constexpr int FOUT = 64;
constexpr int G    = 512;
constexpr int SCAN_ITEMS = 1024;
constexpr int NB_SCAN = (N + SCAN_ITEMS - 1) / SCAN_ITEMS;   // 49

static __device__ __forceinline__ ushort_t f2bf(float f) {
    uint_t u = __float_as_uint(f);
    return (ushort_t)((u + 0x7FFFu + ((u >> 16) & 1u)) >> 16);   // RNE
}
static __device__ __forceinline__ float bflo(uint_t v) { return __uint_as_float(v << 16); }
static __device__ __forceinline__ float bfhi(uint_t v) { return __uint_as_float(v & 0xFFFF0000u); }

// degree + per-edge rank capture (rank store is sequential)
__global__ void k_deg(const int* __restrict__ dst, int* __restrict__ edeg,
                      int* __restrict__ rank) {
    int e = blockIdx.x * blockDim.x + threadIdx.x;
    if (e < E) rank[e] = atomicAdd(&edeg[dst[e]], 1);
}

// block-level exclusive scan of edeg (1024 items / block)
__global__ __launch_bounds__(256) void k_scan1(const int* __restrict__ edeg,
                                               int* __restrict__ row_ptr,
                                               int* __restrict__ bsum) {
    __shared__ int s[256];
    int t = threadIdx.x;
    int base = blockIdx.x * SCAN_ITEMS + t * 4;
    int v0 = (base + 0 < N) ? edeg[base + 0] : 0;
    int v1 = (base + 1 < N) ? edeg[base + 1] : 0;
    int v2 = (base + 2 < N) ? edeg[base + 2] : 0;
    int v3 = (base + 3 < N) ? edeg[base + 3] : 0;
    int tsum = v0 + v1 + v2 + v3;
    s[t] = tsum;
    __syncthreads();
    for (int off = 1; off < 256; off <<= 1) {
        int add = (t >= off) ? s[t - off] : 0;
        __syncthreads();
        s[t] += add;
        __syncthreads();
    }
    int texcl = s[t] - tsum;
    if (t == 255) bsum[blockIdx.x] = s[255];
    if (base + 0 < N) row_ptr[base + 0] = texcl;
    if (base + 1 < N) row_ptr[base + 1] = texcl + v0;
    if (base + 2 < N) row_ptr[base + 2] = texcl + v0 + v1;
    if (base + 3 < N) row_ptr[base + 3] = texcl + v0 + v1 + v2;
}

__global__ void k_scan2(int* __restrict__ bsum) {
    if (threadIdx.x == 0 && blockIdx.x == 0) {
        int run = 0;
        for (int b = 0; b < NB_SCAN; ++b) { int v = bsum[b]; bsum[b] = run; run += v; }
    }
}

// finalize row_ptr, dinv, and build xd = bf16(dinv ⊙ x)  (one wave per node)
__global__ __launch_bounds__(256) void k_scan3x(const int* __restrict__ edeg,
                                                int* __restrict__ row_ptr,
                                                const int* __restrict__ bsum,
                                                float* __restrict__ dinv,
                                                const float* __restrict__ x,
                                                ushort_t* __restrict__ xd) {
    int wv = threadIdx.x >> 6, lane = threadIdx.x & 63;
    int i = blockIdx.x * 4 + wv;
    if (i >= N) return;
    int rp = row_ptr[i] + bsum[i >> 10];           // SCAN_ITEMS = 1024
    float di = rsqrtf(1.0f + (float)edeg[i]);
    if (lane == 0) {
        row_ptr[i] = rp;
        dinv[i] = di;
        if (i == 0) row_ptr[N] = E;
    }
    xd[(size_t)i * 64 + lane] = f2bf(di * x[(size_t)i * 64 + lane]);
}

// non-atomic scatter: slot = row_ptr[dst] + rank
__global__ void k_scatter(const int* __restrict__ src, const int* __restrict__ dst,
                          const int* __restrict__ rank, const int* __restrict__ row_ptr,
                          int* __restrict__ csr) {
    int e = blockIdx.x * blockDim.x + threadIdx.x;
    if (e >= E) return;
    csr[row_ptr[dst[e]] + rank[e]] = src[e];
}

// out[i] = (BIAS? b : 0) + dinv[i] * ( tbl[i] + sum_e tbl[csr_e] )   [tbl in bf16]
// one wave per node; lane = (edge-parity sub, feature-pair fp): 2 edges per issue,
// u32 (2x bf16) per lane; fp32 accumulate; halves combined via shfl_xor(32).
template <bool BIAS>
__global__ __launch_bounds__(256) void k_agg(const ushort_t* __restrict__ tbl,
                                             const int* __restrict__ rp,
                                             const int* __restrict__ csr,
                                             const float* __restrict__ dinv,
                                             const float* __restrict__ bias,
                                             float* __restrict__ outb) {
    int wv = threadIdx.x >> 6, lane = threadIdx.x & 63;
    int sub = lane >> 5, fp = lane & 31;
    int node = blockIdx.x * 4 + wv;
    if (node >= N) return;
    int beg = rp[node], end = rp[node + 1];

    uint_t sv = ((const uint_t*)(tbl + (size_t)node * 64))[fp];
    float sx = 0.f, sy = 0.f;

    int e = beg;
    for (; e + 32 <= end; e += 32) {       // 32 edges per iteration (16 per half-wave)
        int s[16];
#pragma unroll
        for (int j = 0; j < 16; ++j) s[j] = csr[e + 2 * j + sub];
        uint_t v[16];
#pragma unroll
        for (int j = 0; j < 16; ++j)
            v[j] = ((const uint_t*)(tbl + (size_t)s[j] * 64))[fp];
#pragma unroll
        for (int j = 0; j < 16; ++j) { sx += bflo(v[j]); sy += bfhi(v[j]); }
    }
    if (e < end) {                         // masked block: clamped index, zeroed value
        int last = end - 1;
        int s[16];
#pragma unroll
        for (int j = 0; j < 16; ++j) s[j] = csr[min(e + 2 * j + sub, last)];
        uint_t v[16];
#pragma unroll
        for (int j = 0; j < 16; ++j)
            v[j] = ((const uint_t*)(tbl + (size_t)s[j] * 64))[fp];
#pragma unroll
        for (int j = 0; j < 16; ++j) {
            bool ok = (e + 2 * j + sub) < end;
            sx += ok ? bflo(v[j]) : 0.f;
            sy += ok ? bfhi(v[j]) : 0.f;
        }
    }
    // combine edge sums across half-waves, add self once
    float ex = sx + __shfl_xor(sx, 32, 64);
    float ey = sy + __shfl_xor(sy, 32, 64);
    float di = dinv[node];
    float2 res;
    res.x = di * (bflo(sv) + ex);
    res.y = di * (bfhi(sv) + ey);
    if (BIAS) {
        float2 bb = ((const float2*)bias)[fp];
        res.x += bb.x;
        res.y += bb.y;
    }
    if (sub == 0)
        ((float2*)(outb + (size_t)node * 64))[fp] = res;
}

// fused: h2d = bf16( dinv ⊙ ( relu(xa @ W1 + b1) @ W2 ) );  64 nodes / 256-thread block
// LDS 48KB (3 blocks/CU): phase A {W1[64x128] 32KB | Xs[64x64] 16KB}
//                      -> phase B {H1 swizzled 32KB | W2 streamed in 2x16KB halves}
__global__ __launch_bounds__(256) void k_gemm_fused(const float* __restrict__ xa,
                                                    const float* __restrict__ W1,
                                                    const float* __restrict__ b1,
                                                    const float* __restrict__ W2,
                                                    const float* __restrict__ dinv,
                                                    ushort_t* __restrict__ h2d) {
    __shared__ float sm[12288];         // 48 KB
    float* Ws1 = sm;                    // phase A: [64k][128c]
    float4* Xs4 = (float4*)(sm + 8192); // phase A: [64r][16 float4]
    float* H1  = sm;                    // phase B: swizzled [128k][64r]
    float* Ws2 = sm + 8192;             // phase B: [64k][64c] per half
    int t = threadIdx.x;
    int n0 = blockIdx.x * 64;

    // stage W1 + Xs
    float4* sm4 = (float4*)sm;
    const float4* W14 = (const float4*)W1;
#pragma unroll
    for (int i = 0; i < 8; ++i) sm4[t + i * 256] = W14[t + i * 256];
    const float4* xa4 = (const float4*)xa;
#pragma unroll
    for (int i = 0; i < 4; ++i) {
        int j = t + i * 256;
        int r = j >> 4, c4 = j & 15;
        int n = n0 + r;
        Xs4[j] = (n < N) ? xa4[(size_t)n * 16 + c4] : float4{0.f, 0.f, 0.f, 0.f};
    }
    __syncthreads();

    // phase A: acc[rr][c] for rows rowi+8rr, cols 4colg+c (of 128)
    int colg = t & 31, rowi = t >> 5;
    float acc[8][4] = {};
#pragma unroll
    for (int k4 = 0; k4 < 16; ++k4) {
        float4 w0 = ((float4*)(Ws1 + (4 * k4 + 0) * FMID))[colg];
        float4 w1 = ((float4*)(Ws1 + (4 * k4 + 1) * FMID))[colg];
        float4 w2 = ((float4*)(Ws1 + (4 * k4 + 2) * FMID))[colg];
        float4 w3 = ((float4*)(Ws1 + (4 * k4 + 3) * FMID))[colg];
#pragma unroll
        for (int rr = 0; rr < 8; ++rr) {
            float4 xv = Xs4[(rowi + rr * 8) * 16 + k4];
            acc[rr][0] += xv.x * w0.x + xv.y * w1.x + xv.z * w2.x + xv.w * w3.x;
            acc[rr][1] += xv.x * w0.y + xv.y * w1.y + xv.z * w2.y + xv.w * w3.y;
            acc[rr][2] += xv.x * w0.z + xv.y * w1.z + xv.z * w2.z + xv.w * w3.z;
            acc[rr][3] += xv.x * w0.w + xv.y * w1.w + xv.z * w2.w + xv.w * w3.w;
        }
    }
    float4 bb = ((const float4*)b1)[colg];
    __syncthreads();   // all reads of Ws1/Xs done -> safe to overwrite

    // write relu(h1+b1) into H1, swizzle addr = k*64 + ((row + (k>>2)) & 63)
#pragma unroll
    for (int rr = 0; rr < 8; ++rr) {
        int row = rowi + rr * 8;
        int k0 = 4 * colg;
        H1[(k0 + 0) * 64 + ((row + colg) & 63)] = fmaxf(acc[rr][0] + bb.x, 0.f);
        H1[(k0 + 1) * 64 + ((row + colg) & 63)] = fmaxf(acc[rr][1] + bb.y, 0.f);
        H1[(k0 + 2) * 64 + ((row + colg) & 63)] = fmaxf(acc[rr][2] + bb.z, 0.f);
        H1[(k0 + 3) * 64 + ((row + colg) & 63)] = fmaxf(acc[rr][3] + bb.w, 0.f);
    }
    // stage W2 rows 0..63 (16KB) into dead Xs region
    float4* Ws24 = (float4*)Ws2;
    const float4* W24 = (const float4*)W2;
#pragma unroll
    for (int i = 0; i < 4; ++i) Ws24[t + i * 256] = W24[t + i * 256];
    __syncthreads();

    // phase B: rows rowi2+16rr (64), cols 4colg2+c (of 64)
    int colg2 = t & 15, rowi2 = t >> 4;
    float acc2[4][4] = {};
#pragma unroll 4
    for (int k = 0; k < 64; ++k) {
        float4 w = ((float4*)(Ws2 + k * FOUT))[colg2];
        int ks = k >> 2;
#pragma unroll
        for (int rr = 0; rr < 4; ++rr) {
            int row = rowi2 + 16 * rr;
            float xv = H1[k * 64 + ((row + ks) & 63)];
            acc2[rr][0] += xv * w.x;
            acc2[rr][1] += xv * w.y;
            acc2[rr][2] += xv * w.z;
            acc2[rr][3] += xv * w.w;
        }
    }
    __syncthreads();
    // stage W2 rows 64..127
#pragma unroll
    for (int i = 0; i < 4; ++i) Ws24[t + i * 256] = W24[1024 + t + i * 256];
    __syncthreads();
#pragma unroll 4
    for (int k = 64; k < 128; ++k) {
        float4 w = ((float4*)(Ws2 + (k - 64) * FOUT))[colg2];
        int ks = k >> 2;
#pragma unroll
        for (int rr = 0; rr < 4; ++rr) {
            int row = rowi2 + 16 * rr;
            float xv = H1[k * 64 + ((row + ks) & 63)];
            acc2[rr][0] += xv * w.x;
            acc2[rr][1] += xv * w.y;
            acc2[rr][2] += xv * w.z;
            acc2[rr][3] += xv * w.w;
        }
    }
#pragma unroll
    for (int rr = 0; rr < 4; ++rr) {
        int n = n0 + rowi2 + 16 * rr;
        if (n < N) {
            float di = dinv[n];
            uint_t lo = (uint_t)f2bf(di * acc2[rr][0]) | ((uint_t)f2bf(di * acc2[rr][1]) << 16);
            uint_t hi = (uint_t)f2bf(di * acc2[rr][2]) | ((uint_t)f2bf(di * acc2[rr][3]) << 16);
            uint2 o = {lo, hi};
            ((uint2*)(h2d + (size_t)n * 64))[colg2] = o;
        }
    }
}

// one block (4 waves) per graph; batch sorted -> binary search node range
__global__ __launch_bounds__(256) void k_pool(const float* __restrict__ o2,
                                              const int* __restrict__ batch,
                                              float* __restrict__ out) {
    __shared__ float red[256];
    int g = blockIdx.x;
    int wv = threadIdx.x >> 6, lane = threadIdx.x & 63;
    int lo = 0, hi = N;
    while (lo < hi) { int m = (lo + hi) >> 1; if (batch[m] < g) lo = m + 1; else hi = m; }
    int start = lo;
    hi = N;
    while (lo < hi) { int m = (lo + hi) >> 1; if (batch[m] < g + 1) lo = m + 1; else hi = m; }
    int end = lo;
    float acc = 0.f;
    for (int n = start + wv; n < end; n += 4) acc += o2[(size_t)n * FOUT + lane];
    red[threadIdx.x] = acc;
    __syncthreads();
    if (wv == 0) {
        float v = red[lane] + red[64 + lane] + red[128 + lane] + red[192 + lane];
        out[g * FOUT + lane] = v / fmaxf((float)(end - start), 1.f);
    }
}

extern "C" void kernel_launch(void* const* d_in, const int* in_sizes, int n_in,
                              void* d_out, int out_size, void* d_ws, size_t ws_size,
                              hipStream_t stream) {
    const float* x     = (const float*)d_in[0];
    const int*   ei    = (const int*)d_in[1];
    const int*   batch = (const int*)d_in[2];
    const float* W1    = (const float*)d_in[3];
    const float* b1    = (const float*)d_in[4];
    const float* W2    = (const float*)d_in[5];
    const float* b2    = (const float*)d_in[6];
    float* out = (float*)d_out;

    const int* srcp = ei;        // edge_index[0]
    const int* dstp = ei + E;    // edge_index[1]

    char* ws = (char*)d_ws;
    int*      edeg    = (int*)     (ws + 0);          //   200,000 -> 200,704
    int*      rank    = (int*)     (ws + 200704);     // 3,200,000 -> 3,400,704
    float*    dinv    = (float*)   (ws + 3400704);    //   200,000 -> 3,601,408
    int*      row_ptr = (int*)     (ws + 3601408);    //   200,004 -> 3,802,112
    int*      bsum    = (int*)     (ws + 3802112);    //       512 -> 3,802,624
    int*      csr     = (int*)     (ws + 3802624);    // 3,200,000 -> 7,002,624
    ushort_t* xd      = (ushort_t*)(ws + 7002624);    // 6,400,000 -> 13,402,624
    float*    xa      = (float*)   (ws + 13402624);   // 12,800,000 -> 26,202,624
    ushort_t* h2d     = (ushort_t*)(ws + 26202624);   // 6,400,000 -> 32,602,624
    float*    o2      = xa;                           // xa dead after gemm_fused

    dim3 B(256);

    hipMemsetAsync(edeg, 0, N * sizeof(int), stream);
    k_deg<<<dim3((E + 255) / 256), B, 0, stream>>>(dstp, edeg, rank);
    k_scan1<<<dim3(NB_SCAN), B, 0, stream>>>(edeg, row_ptr, bsum);
    k_scan2<<<dim3(1), dim3(64), 0, stream>>>(bsum);
    k_scan3x<<<dim3((N + 3) / 4), B, 0, stream>>>(edeg, row_ptr, bsum, dinv, x, xd);
    k_scatter<<<dim3((E + 255) / 256), B, 0, stream>>>(srcp, dstp, rank, row_ptr, csr);

    k_agg<false><<<dim3((N + 3) / 4), B, 0, stream>>>(xd, row_ptr, csr, dinv, nullptr, xa);
    k_gemm_fused<<<dim3((N + 63) / 64), B, 0, stream>>>(xa, W1, b1, W2, dinv, h2d);
    k_agg<true><<<dim3((N + 3) / 4), B, 0, stream>>>(h2d, row_ptr, csr, dinv, b2, o2);
    k_pool<<<dim3(G), B, 0, stream>>>(o2, batch, out);
}

// Round 8
// 145.974 us; speedup vs baseline: 15.8034x; 1.1867x over previous
//
#include <hip/hip_runtime.h>

typedef unsigned short ushort_t;
typedef unsigned int uint_t;
typedef _Float16 f16;
typedef _Float16 f16x8 __attribute__((ext_vector_type(8)));
typedef _Float16 f16x2 __attribute__((ext_vector_type(2)));
typedef float f32x4 __attribute__((ext_vector_type(4)));

constexpr int N    = 50000;
constexpr int E    = 800000;
constexpr int FMID = 128;
constexpr int G    = 512;
constexpr int SCAN_ITEMS = 1024;
constexpr int NB_SCAN = (N + SCAN_ITEMS - 1) / SCAN_ITEMS;   // 49

// degree + per-edge rank capture (rank store is sequential)
__global__ void k_deg(const int* __restrict__ dst, int* __restrict__ edeg,
                      int* __restrict__ rank) {
    int e = blockIdx.x * blockDim.x + threadIdx.x;
    if (e < E) rank[e] = atomicAdd(&edeg[dst[e]], 1);
}

// block-level exclusive scan of edeg (1024 items / block)
__global__ __launch_bounds__(256) void k_scan1(const int* __restrict__ edeg,
                                               int* __restrict__ row_ptr,
                                               int* __restrict__ bsum) {
    __shared__ int s[256];
    int t = threadIdx.x;
    int base = blockIdx.x * SCAN_ITEMS + t * 4;
    int v0 = (base + 0 < N) ? edeg[base + 0] : 0;
    int v1 = (base + 1 < N) ? edeg[base + 1] : 0;
    int v2 = (base + 2 < N) ? edeg[base + 2] : 0;
    int v3 = (base + 3 < N) ? edeg[base + 3] : 0;
    int tsum = v0 + v1 + v2 + v3;
    s[t] = tsum;
    __syncthreads();
    for (int off = 1; off < 256; off <<= 1) {
        int add = (t >= off) ? s[t - off] : 0;
        __syncthreads();
        s[t] += add;
        __syncthreads();
    }
    int texcl = s[t] - tsum;
    if (t == 255) bsum[blockIdx.x] = s[255];
    if (base + 0 < N) row_ptr[base + 0] = texcl;
    if (base + 1 < N) row_ptr[base + 1] = texcl + v0;
    if (base + 2 < N) row_ptr[base + 2] = texcl + v0 + v1;
    if (base + 3 < N) row_ptr[base + 3] = texcl + v0 + v1 + v2;
}

__global__ void k_scan2(int* __restrict__ bsum) {
    if (threadIdx.x == 0 && blockIdx.x == 0) {
        int run = 0;
        for (int b = 0; b < NB_SCAN; ++b) { int v = bsum[b]; bsum[b] = run; run += v; }
    }
}

// finalize row_ptr, dinv, and build xd = f16(dinv ⊙ x)  (one wave per node)
__global__ __launch_bounds__(256) void k_scan3x(const int* __restrict__ edeg,
                                                int* __restrict__ row_ptr,
                                                const int* __restrict__ bsum,
                                                float* __restrict__ dinv,
                                                const float* __restrict__ x,
                                                f16* __restrict__ xd) {
    int wv = threadIdx.x >> 6, lane = threadIdx.x & 63;
    int i = blockIdx.x * 4 + wv;
    if (i >= N) return;
    int rp = row_ptr[i] + bsum[i >> 10];           // SCAN_ITEMS = 1024
    float di = rsqrtf(1.0f + (float)edeg[i]);
    if (lane == 0) {
        row_ptr[i] = rp;
        dinv[i] = di;
        if (i == 0) row_ptr[N] = E;
    }
    xd[(size_t)i * 64 + lane] = (f16)(di * x[(size_t)i * 64 + lane]);
}

// repack W1,W2 into MFMA B-fragment order (f16), one 16B frag per lane per tile
// W1f idx = ((kk*8+c)*64 + lane)*8 + j  ->  W1[(32kk+8*(lane>>4)+j)*128 + 16c+(lane&15)]
// W2f idx = ((kk*4+c)*64 + lane)*8 + j  ->  W2[(32kk+8*(lane>>4)+j)*64  + 16c+(lane&15)]
__global__ void k_wconv(const float* __restrict__ W1, const float* __restrict__ W2,
                        f16* __restrict__ W1f, f16* __restrict__ W2f) {
    int idx = blockIdx.x * blockDim.x + threadIdx.x;
    if (idx < 8192) {
        int j = idx & 7, lane = (idx >> 3) & 63, c = (idx >> 9) & 7, kk = idx >> 12;
        int k = 32 * kk + 8 * (lane >> 4) + j, col = 16 * c + (lane & 15);
        W1f[idx] = (f16)W1[k * 128 + col];
    } else if (idx < 16384) {
        int t2 = idx - 8192;
        int j = t2 & 7, lane = (t2 >> 3) & 63, c = (t2 >> 9) & 3, kk = (t2 >> 11) & 3;
        int k = 32 * kk + 8 * (lane >> 4) + j, col = 16 * c + (lane & 15);
        W2f[t2] = (f16)W2[k * 64 + col];
    }
}

// non-atomic scatter: slot = row_ptr[dst] + rank
__global__ void k_scatter(const int* __restrict__ src, const int* __restrict__ dst,
                          const int* __restrict__ rank, const int* __restrict__ row_ptr,
                          int* __restrict__ csr) {
    int e = blockIdx.x * blockDim.x + threadIdx.x;
    if (e >= E) return;
    csr[row_ptr[dst[e]] + rank[e]] = src[e];
}

// out[i] = (BIAS? b : 0) + dinv[i] * ( tbl[i] + sum_e tbl[csr_e] )   [tbl f16]
// one wave per node; lane = (edge-parity sub, feature-pair fp): 2 edges per issue
template <bool BIAS, bool F16OUT>
__global__ __launch_bounds__(256) void k_agg(const f16* __restrict__ tbl,
                                             const int* __restrict__ rp,
                                             const int* __restrict__ csr,
                                             const float* __restrict__ dinv,
                                             const float* __restrict__ bias,
                                             float* __restrict__ outf,
                                             f16* __restrict__ outh) {
    int wv = threadIdx.x >> 6, lane = threadIdx.x & 63;
    int sub = lane >> 5, fp = lane & 31;
    int node = blockIdx.x * 4 + wv;
    if (node >= N) return;
    int beg = rp[node], end = rp[node + 1];

    uint_t sv = ((const uint_t*)(tbl + (size_t)node * 64))[fp];
    float sx = 0.f, sy = 0.f;

    int e = beg;
    for (; e + 32 <= end; e += 32) {       // 32 edges per iteration (16 per half-wave)
        int s[16];
#pragma unroll
        for (int j = 0; j < 16; ++j) s[j] = csr[e + 2 * j + sub];
        uint_t v[16];
#pragma unroll
        for (int j = 0; j < 16; ++j)
            v[j] = ((const uint_t*)(tbl + (size_t)s[j] * 64))[fp];
#pragma unroll
        for (int j = 0; j < 16; ++j) {
            f16x2 h = __builtin_bit_cast(f16x2, v[j]);
            sx += (float)h.x; sy += (float)h.y;
        }
    }
    if (e < end) {                         // masked block: clamped index, zeroed value
        int last = end - 1;
        int s[16];
#pragma unroll
        for (int j = 0; j < 16; ++j) s[j] = csr[min(e + 2 * j + sub, last)];
        uint_t v[16];
#pragma unroll
        for (int j = 0; j < 16; ++j)
            v[j] = ((const uint_t*)(tbl + (size_t)s[j] * 64))[fp];
#pragma unroll
        for (int j = 0; j < 16; ++j) {
            f16x2 h = __builtin_bit_cast(f16x2, v[j]);
            bool ok = (e + 2 * j + sub) < end;
            sx += ok ? (float)h.x : 0.f;
            sy += ok ? (float)h.y : 0.f;
        }
    }
    float ex = sx + __shfl_xor(sx, 32, 64);
    float ey = sy + __shfl_xor(sy, 32, 64);
    f16x2 sh = __builtin_bit_cast(f16x2, sv);
    float di = dinv[node];
    float rx = di * ((float)sh.x + ex);
    float ry = di * ((float)sh.y + ey);
    if (BIAS) {
        float2 bb = ((const float2*)bias)[fp];
        rx += bb.x; ry += bb.y;
    }
    if (sub == 0) {
        if (F16OUT) {
            f16x2 o = {(f16)rx, (f16)ry};
            ((uint_t*)outh)[(size_t)node * 32 + fp] = __builtin_bit_cast(uint_t, o);
        } else {
            ((float2*)(outf + (size_t)node * 64))[fp] = make_float2(rx, ry);
        }
    }
}

// fused MFMA GEMM: h2d = f16( dinv ⊙ ( relu(xab @ W1 + b1) @ W2 ) )
// 64 nodes / 256-thread block; wave w owns rows 16w..16w+15 end-to-end (no barrier).
// H1 staged in 16KB LDS, XOR-swizzled: addr ^= ((row&3)<<4) ^ (((row>>2)&3)<<5).
__global__ __launch_bounds__(256) void k_gemm_mfma(const f16* __restrict__ xab,
                                                   const f16* __restrict__ W1f,
                                                   const float* __restrict__ b1,
                                                   const f16* __restrict__ W2f,
                                                   const float* __restrict__ dinv,
                                                   f16* __restrict__ h2d) {
    __shared__ f16 H1[64 * 128];   // 16 KB
    int t = threadIdx.x;
    int w = t >> 6, l = t & 63;
    int q = l >> 4, m = l & 15;
    int n0 = blockIdx.x * 64;
    int rbase = 16 * w;

    // ---- phase A: h1 rows rbase..rbase+15, cols 0..127
    f16x8 afr0, afr1;
    {
        int row = n0 + rbase + m;
        if (row >= N) row = N - 1;
        const f16* rp_ = xab + (size_t)row * 64 + q * 8;
        afr0 = *(const f16x8*)(rp_);
        afr1 = *(const f16x8*)(rp_ + 32);
    }
    f32x4 acc[8];
#pragma unroll
    for (int c = 0; c < 8; ++c) acc[c] = (f32x4){0.f, 0.f, 0.f, 0.f};
    const f16x8* W1v = (const f16x8*)W1f;
#pragma unroll
    for (int c = 0; c < 8; ++c) {
        f16x8 b0 = W1v[(0 * 8 + c) * 64 + l];
        f16x8 b1v = W1v[(1 * 8 + c) * 64 + l];
        acc[c] = __builtin_amdgcn_mfma_f32_16x16x32_f16(afr0, b0, acc[c], 0, 0, 0);
        acc[c] = __builtin_amdgcn_mfma_f32_16x16x32_f16(afr1, b1v, acc[c], 0, 0, 0);
    }
    // epilogue A -> LDS (own band only; no cross-wave sharing)
#pragma unroll
    for (int c = 0; c < 8; ++c) {
        float bias = b1[16 * c + m];
#pragma unroll
        for (int r = 0; r < 4; ++r) {
            int row = rbase + 4 * q + r;
            int col = 16 * c + m;
            float hv = fmaxf(acc[c][r] + bias, 0.f);
            int addr = row * 256 + col * 2;
            addr ^= ((row & 3) << 4) ^ (((row >> 2) & 3) << 5);
            *(f16*)((char*)H1 + addr) = (f16)hv;
        }
    }
    // ---- phase B: h2 rows rbase..rbase+15, cols 0..63 (reads own band; lgkm waits only)
    f16x8 a2[4];
#pragma unroll
    for (int kk = 0; kk < 4; ++kk) {
        int row = rbase + m;
        int addr = row * 256 + kk * 64 + q * 16;
        addr ^= ((row & 3) << 4) ^ (((row >> 2) & 3) << 5);
        a2[kk] = *(const f16x8*)((char*)H1 + addr);
    }
    f32x4 acc2[4];
#pragma unroll
    for (int c = 0; c < 4; ++c) acc2[c] = (f32x4){0.f, 0.f, 0.f, 0.f};
    const f16x8* W2v = (const f16x8*)W2f;
#pragma unroll
    for (int c = 0; c < 4; ++c) {
#pragma unroll
        for (int kk = 0; kk < 4; ++kk) {
            f16x8 b = W2v[(kk * 4 + c) * 64 + l];
            acc2[c] = __builtin_amdgcn_mfma_f32_16x16x32_f16(a2[kk], b, acc2[c], 0, 0, 0);
        }
    }
#pragma unroll
    for (int r = 0; r < 4; ++r) {
        int n = n0 + rbase + 4 * q + r;
        if (n < N) {
            float di = dinv[n];
#pragma unroll
            for (int c = 0; c < 4; ++c)
                h2d[(size_t)n * 64 + 16 * c + m] = (f16)(di * acc2[c][r]);
        }
    }
}

// one block (4 waves) per graph; batch sorted -> binary search node range
__global__ __launch_bounds__(256) void k_pool(const float* __restrict__ o2,
                                              const int* __restrict__ batch,
                                              float* __restrict__ out) {
    __shared__ float red[256];
    int g = blockIdx.x;
    int wv = threadIdx.x >> 6, lane = threadIdx.x & 63;
    int lo = 0, hi = N;
    while (lo < hi) { int m = (lo + hi) >> 1; if (batch[m] < g) lo = m + 1; else hi = m; }
    int start = lo;
    hi = N;
    while (lo < hi) { int m = (lo + hi) >> 1; if (batch[m] < g + 1) lo = m + 1; else hi = m; }
    int end = lo;
    float acc = 0.f;
    for (int n = start + wv; n < end; n += 4) acc += o2[(size_t)n * 64 + lane];
    red[threadIdx.x] = acc;
    __syncthreads();
    if (wv == 0) {
        float v = red[lane] + red[64 + lane] + red[128 + lane] + red[192 + lane];
        out[g * 64 + lane] = v / fmaxf((float)(end - start), 1.f);
    }
}

extern "C" void kernel_launch(void* const* d_in, const int* in_sizes, int n_in,
                              void* d_out, int out_size, void* d_ws, size_t ws_size,
                              hipStream_t stream) {
    const float* x     = (const float*)d_in[0];
    const int*   ei    = (const int*)d_in[1];
    const int*   batch = (const int*)d_in[2];
    const float* W1    = (const float*)d_in[3];
    const float* b1    = (const float*)d_in[4];
    const float* W2    = (const float*)d_in[5];
    const float* b2    = (const float*)d_in[6];
    float* out = (float*)d_out;

    const int* srcp = ei;        // edge_index[0]
    const int* dstp = ei + E;    // edge_index[1]

    char* ws = (char*)d_ws;
    int*   edeg    = (int*)  (ws + 0);          //   200,000 -> 200,704
    int*   rank    = (int*)  (ws + 200704);     // 3,200,000 -> 3,400,704
    float* dinv    = (float*)(ws + 3400704);    //   200,000 -> 3,601,408
    int*   row_ptr = (int*)  (ws + 3601408);    //   200,004 -> 3,802,112
    int*   bsum    = (int*)  (ws + 3802112);    //       512 -> 3,802,624
    int*   csr     = (int*)  (ws + 3802624);    // 3,200,000 -> 7,002,624
    f16*   xd      = (f16*)  (ws + 7002624);    // 6,400,000 -> 13,402,624
    f16*   xab     = (f16*)  (ws + 13402624);   // 6,400,000 -> 19,802,624
    f16*   h2d     = (f16*)  (ws + 19802624);   // 6,400,000 -> 26,202,624
    float* o2      = (float*)(ws + 7002624);    // 12.8MB, aliases xd+xab (both dead)
    f16*   W1f     = (f16*)  (ws + 26202624);   //    16,384 -> 26,219,008
    f16*   W2f     = (f16*)  (ws + 26219008);   //    16,384 -> 26,235,392

    dim3 B(256);

    hipMemsetAsync(edeg, 0, N * sizeof(int), stream);
    k_deg<<<dim3((E + 255) / 256), B, 0, stream>>>(dstp, edeg, rank);
    k_scan1<<<dim3(NB_SCAN), B, 0, stream>>>(edeg, row_ptr, bsum);
    k_scan2<<<dim3(1), dim3(64), 0, stream>>>(bsum);
    k_scan3x<<<dim3((N + 3) / 4), B, 0, stream>>>(edeg, row_ptr, bsum, dinv, x, xd);
    k_wconv<<<dim3(64), B, 0, stream>>>(W1, W2, W1f, W2f);
    k_scatter<<<dim3((E + 255) / 256), B, 0, stream>>>(srcp, dstp, rank, row_ptr, csr);

    k_agg<false, true><<<dim3((N + 3) / 4), B, 0, stream>>>(xd, row_ptr, csr, dinv,
                                                            nullptr, nullptr, xab);
    k_gemm_mfma<<<dim3((N + 63) / 64), B, 0, stream>>>(xab, W1f, b1, W2f, dinv, h2d);
    k_agg<true, false><<<dim3((N + 3) / 4), B, 0, stream>>>(h2d, row_ptr, csr, dinv,
                                                            b2, o2, nullptr);
    k_pool<<<dim3(G), B, 0, stream>>>(o2, batch, out);
}

// Round 9
// 141.435 us; speedup vs baseline: 16.3106x; 1.0321x over previous
//
#include <hip/hip_runtime.h>

typedef unsigned short ushort_t;
typedef unsigned int uint_t;
typedef _Float16 f16;
typedef _Float16 f16x8 __attribute__((ext_vector_type(8)));
typedef float f32x4 __attribute__((ext_vector_type(4)));

constexpr int N    = 50000;
constexpr int E    = 800000;
constexpr int G    = 512;
constexpr int SCAN_ITEMS = 1024;
constexpr int NB_SCAN = (N + SCAN_ITEMS - 1) / SCAN_ITEMS;   // 49

// zero edeg (50000 ints = 12500 int4)
__global__ void k_zero(int4* __restrict__ p) {
    int i = blockIdx.x * blockDim.x + threadIdx.x;
    if (i < 12500) p[i] = int4{0, 0, 0, 0};
}

// degree + per-edge rank capture (rank store is sequential, u16)
__global__ void k_deg(const int* __restrict__ dst, int* __restrict__ edeg,
                      ushort_t* __restrict__ rank) {
    int e = blockIdx.x * blockDim.x + threadIdx.x;
    if (e < E) rank[e] = (ushort_t)atomicAdd(&edeg[dst[e]], 1);
}

// block-level exclusive scan of edeg (1024 items / block); extra blocks repack W->f16 frags
__global__ __launch_bounds__(256) void k_scan1w(const int* __restrict__ edeg,
                                                int* __restrict__ row_ptr,
                                                int* __restrict__ bsum,
                                                const float* __restrict__ W1,
                                                const float* __restrict__ W2,
                                                f16* __restrict__ W1f,
                                                f16* __restrict__ W2f) {
    __shared__ int s[256];
    int t = threadIdx.x;
    if (blockIdx.x >= NB_SCAN) {
        // W repack: W1f idx ((kk*8+c)*64+lane)*8+j <- W1[(32kk+8*(lane>>4)+j)*128 + 16c+(lane&15)]
        int idx = (blockIdx.x - NB_SCAN) * 256 + t;
        if (idx < 8192) {
            int j = idx & 7, lane = (idx >> 3) & 63, c = (idx >> 9) & 7, kk = idx >> 12;
            int k = 32 * kk + 8 * (lane >> 4) + j, col = 16 * c + (lane & 15);
            W1f[idx] = (f16)W1[k * 128 + col];
        } else {
            int t2 = idx - 8192;
            int j = t2 & 7, lane = (t2 >> 3) & 63, c = (t2 >> 9) & 3, kk = (t2 >> 11) & 3;
            int k = 32 * kk + 8 * (lane >> 4) + j, col = 16 * c + (lane & 15);
            W2f[t2] = (f16)W2[k * 64 + col];
        }
        return;
    }
    int base = blockIdx.x * SCAN_ITEMS + t * 4;
    int v0 = (base + 0 < N) ? edeg[base + 0] : 0;
    int v1 = (base + 1 < N) ? edeg[base + 1] : 0;
    int v2 = (base + 2 < N) ? edeg[base + 2] : 0;
    int v3 = (base + 3 < N) ? edeg[base + 3] : 0;
    int tsum = v0 + v1 + v2 + v3;
    s[t] = tsum;
    __syncthreads();
    for (int off = 1; off < 256; off <<= 1) {
        int add = (t >= off) ? s[t - off] : 0;
        __syncthreads();
        s[t] += add;
        __syncthreads();
    }
    int texcl = s[t] - tsum;
    if (t == 255) bsum[blockIdx.x] = s[255];
    if (base + 0 < N) row_ptr[base + 0] = texcl;
    if (base + 1 < N) row_ptr[base + 1] = texcl + v0;
    if (base + 2 < N) row_ptr[base + 2] = texcl + v0 + v1;
    if (base + 3 < N) row_ptr[base + 3] = texcl + v0 + v1 + v2;
}

// single-wave exclusive scan of the 49 block sums
__global__ void k_scan2(int* __restrict__ bsum) {
    int l = threadIdx.x;                       // 64 threads
    int v = (l < NB_SCAN) ? bsum[l] : 0;
    int incl = v;
#pragma unroll
    for (int off = 1; off < 64; off <<= 1) {
        int tt = __shfl_up(incl, off, 64);
        if (l >= off) incl += tt;
    }
    if (l < NB_SCAN) bsum[l] = incl - v;
}

// finalize row_ptr, dinv, and build xd = f16(dinv ⊙ x)  (one wave per node)
__global__ __launch_bounds__(256) void k_scan3x(const int* __restrict__ edeg,
                                                int* __restrict__ row_ptr,
                                                const int* __restrict__ bsum,
                                                float* __restrict__ dinv,
                                                const float* __restrict__ x,
                                                f16* __restrict__ xd) {
    int wv = threadIdx.x >> 6, lane = threadIdx.x & 63;
    int i = blockIdx.x * 4 + wv;
    if (i >= N) return;
    int rp = row_ptr[i] + bsum[i >> 10];           // SCAN_ITEMS = 1024
    float di = rsqrtf(1.0f + (float)edeg[i]);
    if (lane == 0) {
        row_ptr[i] = rp;
        dinv[i] = di;
        if (i == 0) row_ptr[N] = E;
    }
    xd[(size_t)i * 64 + lane] = (f16)(di * x[(size_t)i * 64 + lane]);
}

// non-atomic scatter: csr16[row_ptr[dst] + rank] = src  (u16 payload)
__global__ void k_scatter(const int* __restrict__ src, const int* __restrict__ dst,
                          const ushort_t* __restrict__ rank, const int* __restrict__ row_ptr,
                          ushort_t* __restrict__ csr) {
    int e = blockIdx.x * blockDim.x + threadIdx.x;
    if (e >= E) return;
    csr[row_ptr[dst[e]] + rank[e]] = (ushort_t)src[e];
}

// out[i] = f16( (BIAS? b : 0) + dinv[i] * ( tbl[i] + sum_e tbl[csr_e] ) )
// lane = (edge-slot sub 0..7, 16B-chunk fp 0..7); 32 edge slots per iteration,
// 4x f16x8 gathers per lane in flight; butterfly reduce over subs; static indexing.
template <bool BIAS>
__global__ __launch_bounds__(256) void k_agg(const f16* __restrict__ tbl,
                                             const int* __restrict__ rp,
                                             const ushort_t* __restrict__ csr,
                                             const float* __restrict__ dinv,
                                             const float* __restrict__ bias,
                                             f16* __restrict__ outh) {
    int wv = threadIdx.x >> 6, l = threadIdx.x & 63;
    int sub = l >> 3, fp = l & 7;
    int node = blockIdx.x * 4 + wv;
    if (node >= N) return;
    int beg = rp[node], end = rp[node + 1];
    const f16x8* tv = (const f16x8*)tbl;            // row s, chunk fp -> tv[s*8+fp]
    f16x8 sv = tv[(size_t)node * 8 + fp];
    float a[8] = {0.f, 0.f, 0.f, 0.f, 0.f, 0.f, 0.f, 0.f};

    int e = beg;
    for (; e + 32 <= end; e += 32) {
        int s0 = csr[e + sub];
        int s1 = csr[e + 8 + sub];
        int s2 = csr[e + 16 + sub];
        int s3 = csr[e + 24 + sub];
        f16x8 v0 = tv[(size_t)s0 * 8 + fp];
        f16x8 v1 = tv[(size_t)s1 * 8 + fp];
        f16x8 v2 = tv[(size_t)s2 * 8 + fp];
        f16x8 v3 = tv[(size_t)s3 * 8 + fp];
#pragma unroll
        for (int j = 0; j < 8; ++j)
            a[j] += ((float)v0[j] + (float)v1[j]) + ((float)v2[j] + (float)v3[j]);
    }
    if (e < end) {                                  // masked block of 32 slots
        int last = end - 1;
        int i0 = e + sub, i1 = e + 8 + sub, i2 = e + 16 + sub, i3 = e + 24 + sub;
        int s0 = csr[min(i0, last)];
        int s1 = csr[min(i1, last)];
        int s2 = csr[min(i2, last)];
        int s3 = csr[min(i3, last)];
        f16x8 v0 = tv[(size_t)s0 * 8 + fp];
        f16x8 v1 = tv[(size_t)s1 * 8 + fp];
        f16x8 v2 = tv[(size_t)s2 * 8 + fp];
        f16x8 v3 = tv[(size_t)s3 * 8 + fp];
        float m0 = i0 < end ? 1.f : 0.f;
        float m1 = i1 < end ? 1.f : 0.f;
        float m2 = i2 < end ? 1.f : 0.f;
        float m3 = i3 < end ? 1.f : 0.f;
#pragma unroll
        for (int j = 0; j < 8; ++j)
            a[j] += (m0 * (float)v0[j] + m1 * (float)v1[j]) +
                    (m2 * (float)v2[j] + m3 * (float)v3[j]);
    }
    // reduce across the 8 edge-slot groups (lanes fp, fp+8, ..., fp+56)
#pragma unroll
    for (int j = 0; j < 8; ++j) {
        a[j] += __shfl_xor(a[j], 8, 64);
        a[j] += __shfl_xor(a[j], 16, 64);
        a[j] += __shfl_xor(a[j], 32, 64);
    }
    float di = dinv[node];
    if (sub == 0) {                                 // 8 lanes store 16B each
        f16x8 o;
#pragma unroll
        for (int j = 0; j < 8; ++j) {
            float r = di * ((float)sv[j] + a[j]);
            if (BIAS) r += bias[fp * 8 + j];
            o[j] = (f16)r;
        }
        *(f16x8*)(outh + (size_t)node * 64 + fp * 8) = o;
    }
}

// fused MFMA GEMM: h2d = f16( dinv ⊙ ( relu(xab @ W1 + b1) @ W2 ) )
// 64 nodes / 256-thread block; wave w owns rows 16w..16w+15 end-to-end (no barrier).
// H1 staged in 16KB LDS, XOR-swizzled: addr ^= ((row&3)<<4) ^ (((row>>2)&3)<<5).
__global__ __launch_bounds__(256) void k_gemm_mfma(const f16* __restrict__ xab,
                                                   const f16* __restrict__ W1f,
                                                   const float* __restrict__ b1,
                                                   const f16* __restrict__ W2f,
                                                   const float* __restrict__ dinv,
                                                   f16* __restrict__ h2d) {
    __shared__ f16 H1[64 * 128];   // 16 KB
    int t = threadIdx.x;
    int w = t >> 6, l = t & 63;
    int q = l >> 4, m = l & 15;
    int n0 = blockIdx.x * 64;
    int rbase = 16 * w;

    // ---- phase A: h1 rows rbase..rbase+15, cols 0..127
    f16x8 afr0, afr1;
    {
        int row = n0 + rbase + m;
        if (row >= N) row = N - 1;
        const f16* rp_ = xab + (size_t)row * 64 + q * 8;
        afr0 = *(const f16x8*)(rp_);
        afr1 = *(const f16x8*)(rp_ + 32);
    }
    f32x4 acc[8];
#pragma unroll
    for (int c = 0; c < 8; ++c) acc[c] = (f32x4){0.f, 0.f, 0.f, 0.f};
    const f16x8* W1v = (const f16x8*)W1f;
#pragma unroll
    for (int c = 0; c < 8; ++c) {
        f16x8 b0 = W1v[(0 * 8 + c) * 64 + l];
        f16x8 b1v = W1v[(1 * 8 + c) * 64 + l];
        acc[c] = __builtin_amdgcn_mfma_f32_16x16x32_f16(afr0, b0, acc[c], 0, 0, 0);
        acc[c] = __builtin_amdgcn_mfma_f32_16x16x32_f16(afr1, b1v, acc[c], 0, 0, 0);
    }
    // epilogue A -> LDS (own band only; no cross-wave sharing)
#pragma unroll
    for (int c = 0; c < 8; ++c) {
        float bias = b1[16 * c + m];
#pragma unroll
        for (int r = 0; r < 4; ++r) {
            int row = rbase + 4 * q + r;
            int col = 16 * c + m;
            float hv = fmaxf(acc[c][r] + bias, 0.f);
            int addr = row * 256 + col * 2;
            addr ^= ((row & 3) << 4) ^ (((row >> 2) & 3) << 5);
            *(f16*)((char*)H1 + addr) = (f16)hv;
        }
    }
    // ---- phase B: h2 rows rbase..rbase+15, cols 0..63 (reads own band; lgkm waits only)
    f16x8 a2[4];
#pragma unroll
    for (int kk = 0; kk < 4; ++kk) {
        int row = rbase + m;
        int addr = row * 256 + kk * 64 + q * 16;
        addr ^= ((row & 3) << 4) ^ (((row >> 2) & 3) << 5);
        a2[kk] = *(const f16x8*)((char*)H1 + addr);
    }
    f32x4 acc2[4];
#pragma unroll
    for (int c = 0; c < 4; ++c) acc2[c] = (f32x4){0.f, 0.f, 0.f, 0.f};
    const f16x8* W2v = (const f16x8*)W2f;
#pragma unroll
    for (int c = 0; c < 4; ++c) {
#pragma unroll
        for (int kk = 0; kk < 4; ++kk) {
            f16x8 b = W2v[(kk * 4 + c) * 64 + l];
            acc2[c] = __builtin_amdgcn_mfma_f32_16x16x32_f16(a2[kk], b, acc2[c], 0, 0, 0);
        }
    }
#pragma unroll
    for (int r = 0; r < 4; ++r) {
        int n = n0 + rbase + 4 * q + r;
        if (n < N) {
            float di = dinv[n];
#pragma unroll
            for (int c = 0; c < 4; ++c)
                h2d[(size_t)n * 64 + 16 * c + m] = (f16)(di * acc2[c][r]);
        }
    }
}

// one block (4 waves) per graph; batch sorted -> binary search node range; o2 in f16
__global__ __launch_bounds__(256) void k_pool(const f16* __restrict__ o2h,
                                              const int* __restrict__ batch,
                                              float* __restrict__ out) {
    __shared__ float red[256];
    int g = blockIdx.x;
    int wv = threadIdx.x >> 6, lane = threadIdx.x & 63;
    int lo = 0, hi = N;
    while (lo < hi) { int m = (lo + hi) >> 1; if (batch[m] < g) lo = m + 1; else hi = m; }
    int start = lo;
    hi = N;
    while (lo < hi) { int m = (lo + hi) >> 1; if (batch[m] < g + 1) lo = m + 1; else hi = m; }
    int end = lo;
    float acc = 0.f;
    for (int n = start + wv; n < end; n += 4) acc += (float)o2h[(size_t)n * 64 + lane];
    red[threadIdx.x] = acc;
    __syncthreads();
    if (wv == 0) {
        float v = red[lane] + red[64 + lane] + red[128 + lane] + red[192 + lane];
        out[g * 64 + lane] = v / fmaxf((float)(end - start), 1.f);
    }
}

extern "C" void kernel_launch(void* const* d_in, const int* in_sizes, int n_in,
                              void* d_out, int out_size, void* d_ws, size_t ws_size,
                              hipStream_t stream) {
    const float* x     = (const float*)d_in[0];
    const int*   ei    = (const int*)d_in[1];
    const int*   batch = (const int*)d_in[2];
    const float* W1    = (const float*)d_in[3];
    const float* b1    = (const float*)d_in[4];
    const float* W2    = (const float*)d_in[5];
    const float* b2    = (const float*)d_in[6];
    float* out = (float*)d_out;

    const int* srcp = ei;        // edge_index[0]
    const int* dstp = ei + E;    // edge_index[1]

    char* ws = (char*)d_ws;
    int*      edeg    = (int*)     (ws + 0);          //   200,000 -> 200,704
    ushort_t* rank16  = (ushort_t*)(ws + 200704);     // 1,600,000 -> 1,801,216
    float*    dinv    = (float*)   (ws + 1801216);    //   200,000 -> 2,001,920
    int*      row_ptr = (int*)     (ws + 2001920);    //   200,004 -> 2,202,624
    int*      bsum    = (int*)     (ws + 2202624);    //       256 -> 2,203,136
    ushort_t* csr16   = (ushort_t*)(ws + 2203136);    // 1,600,000 -> 3,803,648
    f16*      xd      = (f16*)     (ws + 3803648);    // 6,400,000 -> 10,203,648
    f16*      xab     = (f16*)     (ws + 10203648);   // 6,400,000 -> 16,603,648
    f16*      h2d     = (f16*)     (ws + 16603648);   // 6,400,000 -> 23,003,648
    f16*      o2h     = xd;                           // xd dead after first agg
    f16*      W1f     = (f16*)     (ws + 23003648);   //    16,384 -> 23,020,032
    f16*      W2f     = (f16*)     (ws + 23020032);   //    16,384 -> 23,036,416

    dim3 B(256);

    k_zero<<<dim3(49), B, 0, stream>>>((int4*)edeg);
    k_deg<<<dim3((E + 255) / 256), B, 0, stream>>>(dstp, edeg, rank16);
    k_scan1w<<<dim3(NB_SCAN + 64), B, 0, stream>>>(edeg, row_ptr, bsum, W1, W2, W1f, W2f);
    k_scan2<<<dim3(1), dim3(64), 0, stream>>>(bsum);
    k_scan3x<<<dim3((N + 3) / 4), B, 0, stream>>>(edeg, row_ptr, bsum, dinv, x, xd);
    k_scatter<<<dim3((E + 255) / 256), B, 0, stream>>>(srcp, dstp, rank16, row_ptr, csr16);

    k_agg<false><<<dim3((N + 3) / 4), B, 0, stream>>>(xd, row_ptr, csr16, dinv, nullptr, xab);
    k_gemm_mfma<<<dim3((N + 63) / 64), B, 0, stream>>>(xab, W1f, b1, W2f, dinv, h2d);
    k_agg<true><<<dim3((N + 3) / 4), B, 0, stream>>>(h2d, row_ptr, csr16, dinv, b2, o2h);
    k_pool<<<dim3(G), B, 0, stream>>>(o2h, batch, out);
}